// Round 2
// baseline (428.042 us; speedup 1.0000x reference)
//
#include <hip/hip_runtime.h>

#define HH 96
#define WW 96
#define DD 16
#define NG 512
#define NF 32
#define NP (HH * WW * DD)   // 147456 points

#define SEG 4               // gaussian segments (one wave each)
#define SEGN (NG / SEG)     // 128 gaussians per segment
#define PTS 64              // points per block
#define ROWD 17             // dwords per (seg,point) partial row: 32 bf16 + 2 pad (odd -> conflict-free)

// Per-gaussian packed params in d_ws: 12 floats
// [mx,my,mz, a00 | a01,a02,a11,a12 | a22, opacity, pad, pad]

__global__ __launch_bounds__(256) void gr_prep(
    const float* __restrict__ means,
    const float* __restrict__ scales,
    const float* __restrict__ rots,
    const float* __restrict__ opac,
    const float* __restrict__ cam,
    float* __restrict__ gp)
{
    int n = blockIdx.x * blockDim.x + threadIdx.x;
    if (n >= NG) return;

    float mx = means[n * 3 + 0];
    float my = means[n * 3 + 1];
    float mz = means[n * 3 + 2];

    float h0 = cam[0]  * mx + cam[1]  * my + cam[2]  * mz + cam[3];
    float h1 = cam[4]  * mx + cam[5]  * my + cam[6]  * mz + cam[7];
    float h2 = cam[8]  * mx + cam[9]  * my + cam[10] * mz + cam[11];
    float h3 = cam[12] * mx + cam[13] * my + cam[14] * mz + cam[15];
    float ih3 = 1.0f / h3;
    mx = h0 * ih3; my = h1 * ih3; mz = h2 * ih3;

    float qw = rots[n * 4 + 0];
    float qx = rots[n * 4 + 1];
    float qy = rots[n * 4 + 2];
    float qz = rots[n * 4 + 3];
    float qinv = 1.0f / sqrtf(qw * qw + qx * qx + qy * qy + qz * qz);
    qw *= qinv; qx *= qinv; qy *= qinv; qz *= qinv;

    float R00 = 1.0f - 2.0f * (qy * qy + qz * qz);
    float R01 = 2.0f * (qx * qy - qw * qz);
    float R02 = 2.0f * (qx * qz + qw * qy);
    float R10 = 2.0f * (qx * qy + qw * qz);
    float R11 = 1.0f - 2.0f * (qx * qx + qz * qz);
    float R12 = 2.0f * (qy * qz - qw * qx);
    float R20 = 2.0f * (qx * qz - qw * qy);
    float R21 = 2.0f * (qy * qz + qw * qx);
    float R22 = 1.0f - 2.0f * (qx * qx + qy * qy);

    float s0 = scales[n * 3 + 0];
    float s1 = scales[n * 3 + 1];
    float s2 = scales[n * 3 + 2];
    // cov = R diag(s^2) R^T (R orthonormal) => inv_cov = R diag(s^-2) R^T
    float i0 = 1.0f / (s0 * s0);
    float i1 = 1.0f / (s1 * s1);
    float i2 = 1.0f / (s2 * s2);

    float a00 = R00 * R00 * i0 + R01 * R01 * i1 + R02 * R02 * i2;
    float a01 = R00 * R10 * i0 + R01 * R11 * i1 + R02 * R12 * i2;
    float a02 = R00 * R20 * i0 + R01 * R21 * i1 + R02 * R22 * i2;
    float a11 = R10 * R10 * i0 + R11 * R11 * i1 + R12 * R12 * i2;
    float a12 = R10 * R20 * i0 + R11 * R21 * i1 + R12 * R22 * i2;
    float a22 = R20 * R20 * i0 + R21 * R21 * i1 + R22 * R22 * i2;

    float* g = gp + n * 12;
    g[0] = mx;  g[1] = my;  g[2] = mz;  g[3]  = a00;
    g[4] = a01; g[5] = a02; g[6] = a11; g[7]  = a12;
    g[8] = a22; g[9] = opac[n]; g[10] = 0.0f; g[11] = 0.0f;
}

__device__ __forceinline__ unsigned pack_bf16_rne(float a, float b) {
    unsigned ua = __float_as_uint(a);
    unsigned ub = __float_as_uint(b);
    ua = (ua + 0x7fffu + ((ua >> 16) & 1u)) >> 16;
    ub = (ub + 0x7fffu + ((ub >> 16) & 1u)) >> 16;
    return ua | (ub << 16);
}

__device__ __forceinline__ float bf16_lo(unsigned u) { return __uint_as_float(u << 16); }
__device__ __forceinline__ float bf16_hi(unsigned u) { return __uint_as_float(u & 0xffff0000u); }

// Block: 256 threads = 4 waves. Wave s renders gaussian segment [s*128, s*128+128)
// for 64 points, producing partial feature sums + segment transmittance.
// Combine phase composes segments: out = sum_s (prod_{s'<s} T_s') * acc_s.
__global__ __launch_bounds__(256, 6) void gr_render_seg(
    const float* __restrict__ gp,
    const float* __restrict__ feats,
    const float* __restrict__ coords,
    float* __restrict__ out)
{
    __shared__ unsigned accs[SEG * PTS * ROWD];   // bf16 pairs, padded rows
    __shared__ float tseg[SEG][PTS];

    const int tid = threadIdx.x;
    const int s  = tid >> 6;      // segment = wave id
    const int pl = tid & 63;      // point within block
    const int p  = blockIdx.x * PTS + pl;

    const float cx = coords[p * 3 + 0];
    const float cy = coords[p * 3 + 1];
    const float cz = coords[p * 3 + 2];

    float acc[NF];
#pragma unroll
    for (int j = 0; j < NF; ++j) acc[j] = 0.0f;
    float T = 1.0f;

    const int n0 = s * SEGN;
#pragma unroll 2
    for (int i = 0; i < SEGN; ++i) {
        const int n = n0 + i;
        const float4* __restrict__ g4 = (const float4*)(gp + n * 12);
        float4 A = g4[0];   // mx, my, mz, a00
        float4 B = g4[1];   // a01, a02, a11, a12
        float4 C = g4[2];   // a22, opacity, pad, pad

        float dx = cx - A.x;
        float dy = cy - A.y;
        float dz = cz - A.z;
        float t0 = A.w * dx + B.x * dy + B.y * dz;
        float t1 = B.x * dx + B.z * dy + B.w * dz;
        float t2 = B.y * dx + B.w * dy + C.x * dz;
        float mahal = dx * t0 + dy * t1 + dz * t2;
        float alpha = C.y * __expf(-0.5f * mahal);
        float w = T * alpha;
        T *= (1.0f - alpha);

        const float4* __restrict__ f4 = (const float4*)(feats + n * NF);
#pragma unroll
        for (int j = 0; j < 8; ++j) {
            float4 f = f4[j];
            acc[4 * j + 0] = fmaf(w, f.x, acc[4 * j + 0]);
            acc[4 * j + 1] = fmaf(w, f.y, acc[4 * j + 1]);
            acc[4 * j + 2] = fmaf(w, f.z, acc[4 * j + 2]);
            acc[4 * j + 3] = fmaf(w, f.w, acc[4 * j + 3]);
        }
    }

    // Store partials: bf16 pairs, row stride 17 dwords (odd -> <=2-way bank alias, free)
    unsigned* row = &accs[(s * PTS + pl) * ROWD];
#pragma unroll
    for (int j = 0; j < 16; ++j)
        row[j] = pack_bf16_rne(acc[2 * j], acc[2 * j + 1]);
    tseg[s][pl] = T;

    __syncthreads();

    // Combine: thread -> (point pl2, feature-group fg of 8)
    const int pl2 = tid >> 2;
    const int fg  = tid & 3;

    float t0s = tseg[0][pl2];
    float t1s = tseg[1][pl2];
    float t2s = tseg[2][pl2];
    float w1 = t0s;
    float w2 = t0s * t1s;
    float w3 = w2 * t2s;

    float o[8];
    {
        const unsigned* r0 = &accs[(0 * PTS + pl2) * ROWD + fg * 4];
#pragma unroll
        for (int j = 0; j < 4; ++j) {
            unsigned u = r0[j];
            o[2 * j + 0] = bf16_lo(u);
            o[2 * j + 1] = bf16_hi(u);
        }
    }
    {
        const unsigned* r1 = &accs[(1 * PTS + pl2) * ROWD + fg * 4];
#pragma unroll
        for (int j = 0; j < 4; ++j) {
            unsigned u = r1[j];
            o[2 * j + 0] = fmaf(w1, bf16_lo(u), o[2 * j + 0]);
            o[2 * j + 1] = fmaf(w1, bf16_hi(u), o[2 * j + 1]);
        }
    }
    {
        const unsigned* r2 = &accs[(2 * PTS + pl2) * ROWD + fg * 4];
#pragma unroll
        for (int j = 0; j < 4; ++j) {
            unsigned u = r2[j];
            o[2 * j + 0] = fmaf(w2, bf16_lo(u), o[2 * j + 0]);
            o[2 * j + 1] = fmaf(w2, bf16_hi(u), o[2 * j + 1]);
        }
    }
    {
        const unsigned* r3 = &accs[(3 * PTS + pl2) * ROWD + fg * 4];
#pragma unroll
        for (int j = 0; j < 4; ++j) {
            unsigned u = r3[j];
            o[2 * j + 0] = fmaf(w3, bf16_lo(u), o[2 * j + 0]);
            o[2 * j + 1] = fmaf(w3, bf16_hi(u), o[2 * j + 1]);
        }
    }

    float* __restrict__ op = out + (blockIdx.x * PTS + pl2) * NF + fg * 8;
    float4* __restrict__ op4 = (float4*)op;
    op4[0] = make_float4(o[0], o[1], o[2], o[3]);
    op4[1] = make_float4(o[4], o[5], o[6], o[7]);
}

extern "C" void kernel_launch(void* const* d_in, const int* in_sizes, int n_in,
                              void* d_out, int out_size, void* d_ws, size_t ws_size,
                              hipStream_t stream)
{
    const float* means  = (const float*)d_in[0];   // (512,3)
    const float* scales = (const float*)d_in[1];   // (512,3)
    const float* rots   = (const float*)d_in[2];   // (512,4)
    const float* opac   = (const float*)d_in[3];   // (512,1)
    const float* feats  = (const float*)d_in[4];   // (512,32)
    const float* cam    = (const float*)d_in[5];   // (4,4)
    const float* coords = (const float*)d_in[6];   // (96,96,16,3)
    float* out = (float*)d_out;                    // (96,96,16,32) fp32

    float* gp = (float*)d_ws;                      // 512*12 floats = 24 KiB

    gr_prep<<<(NG + 255) / 256, 256, 0, stream>>>(means, scales, rots, opac, cam, gp);
    gr_render_seg<<<NP / PTS, 256, 0, stream>>>(gp, feats, coords, out);
}

// Round 3
// 244.864 us; speedup vs baseline: 1.7481x; 1.7481x over previous
//
#include <hip/hip_runtime.h>

#define NG 512
#define NF 32
#define NP (96 * 96 * 16)   // 147456 points
#define TPB 256

// Per-gaussian packed params in d_ws: 12 floats
// [mx,my,mz, A00,A01,A02,A11,A12,A22, lop2, pad, pad]
// A is inv_cov pre-scaled by 0.5*log2(e); lop2 = log2(opacity)
// so alpha = opacity * exp(-0.5*mahal) = exp2(lop2 - d^T A d).

__global__ __launch_bounds__(256) void gr_prep(
    const float* __restrict__ means,
    const float* __restrict__ scales,
    const float* __restrict__ rots,
    const float* __restrict__ opac,
    const float* __restrict__ cam,
    float* __restrict__ gp)
{
    int n = blockIdx.x * blockDim.x + threadIdx.x;
    if (n >= NG) return;

    float mx = means[n * 3 + 0];
    float my = means[n * 3 + 1];
    float mz = means[n * 3 + 2];

    float h0 = cam[0]  * mx + cam[1]  * my + cam[2]  * mz + cam[3];
    float h1 = cam[4]  * mx + cam[5]  * my + cam[6]  * mz + cam[7];
    float h2 = cam[8]  * mx + cam[9]  * my + cam[10] * mz + cam[11];
    float h3 = cam[12] * mx + cam[13] * my + cam[14] * mz + cam[15];
    float ih3 = 1.0f / h3;
    mx = h0 * ih3; my = h1 * ih3; mz = h2 * ih3;

    float qw = rots[n * 4 + 0];
    float qx = rots[n * 4 + 1];
    float qy = rots[n * 4 + 2];
    float qz = rots[n * 4 + 3];
    float qinv = 1.0f / sqrtf(qw * qw + qx * qx + qy * qy + qz * qz);
    qw *= qinv; qx *= qinv; qy *= qinv; qz *= qinv;

    float R00 = 1.0f - 2.0f * (qy * qy + qz * qz);
    float R01 = 2.0f * (qx * qy - qw * qz);
    float R02 = 2.0f * (qx * qz + qw * qy);
    float R10 = 2.0f * (qx * qy + qw * qz);
    float R11 = 1.0f - 2.0f * (qx * qx + qz * qz);
    float R12 = 2.0f * (qy * qz - qw * qx);
    float R20 = 2.0f * (qx * qz - qw * qy);
    float R21 = 2.0f * (qy * qz + qw * qx);
    float R22 = 1.0f - 2.0f * (qx * qx + qy * qy);

    float s0 = scales[n * 3 + 0];
    float s1 = scales[n * 3 + 1];
    float s2 = scales[n * 3 + 2];
    // cov = R diag(s^2) R^T (R orthonormal) => inv_cov = R diag(s^-2) R^T
    // fold in 0.5*log2(e) so exponent is computed in base 2 directly
    const float es = 0.7213475204444817f;  // 0.5 * log2(e)
    float i0 = es / (s0 * s0);
    float i1 = es / (s1 * s1);
    float i2 = es / (s2 * s2);

    float a00 = R00 * R00 * i0 + R01 * R01 * i1 + R02 * R02 * i2;
    float a01 = R00 * R10 * i0 + R01 * R11 * i1 + R02 * R12 * i2;
    float a02 = R00 * R20 * i0 + R01 * R21 * i1 + R02 * R22 * i2;
    float a11 = R10 * R10 * i0 + R11 * R11 * i1 + R12 * R12 * i2;
    float a12 = R10 * R20 * i0 + R11 * R21 * i1 + R12 * R22 * i2;
    float a22 = R20 * R20 * i0 + R21 * R21 * i1 + R22 * R22 * i2;

    float* g = gp + n * 12;
    g[0] = mx;  g[1] = my;  g[2] = mz;
    g[3] = a00; g[4] = a01; g[5] = a02;
    g[6] = a11; g[7] = a12; g[8] = a22;
    g[9] = __log2f(opac[n]);
    g[10] = 0.0f; g[11] = 0.0f;
}

// One thread per point, full 512-gaussian cumprod per thread (keeps gp loads
// loop-uniform -> scalar s_load path; R2 showed breaking uniformity costs 2x).
// feats staged once per block into LDS; inner-loop feature reads are
// wave-uniform ds_read_b128 broadcasts.
__global__ __launch_bounds__(256) void gr_render(
    const float* __restrict__ gp,
    const float* __restrict__ feats,
    const float* __restrict__ coords,
    float* __restrict__ out)
{
    __shared__ float4 fsh[NG * NF / 4];   // 4096 float4 = 64 KB

    const int tid = threadIdx.x;
    const float4* __restrict__ fg = (const float4*)feats;
#pragma unroll
    for (int i = 0; i < 16; ++i)
        fsh[tid + 256 * i] = fg[tid + 256 * i];
    __syncthreads();

    const int p = blockIdx.x * TPB + tid;
    const float cx = coords[p * 3 + 0];
    const float cy = coords[p * 3 + 1];
    const float cz = coords[p * 3 + 2];

    float acc[NF];
#pragma unroll
    for (int j = 0; j < NF; ++j) acc[j] = 0.0f;
    float T = 1.0f;

#pragma unroll 4
    for (int n = 0; n < NG; ++n) {
        const float* __restrict__ g = gp + n * 12;   // loop-uniform -> s_load
        float dx = cx - g[0];
        float dy = cy - g[1];
        float dz = cz - g[2];
        float t0 = g[3] * dx + g[4] * dy + g[5] * dz;
        float t1 = g[4] * dx + g[6] * dy + g[7] * dz;
        float t2 = g[5] * dx + g[7] * dy + g[8] * dz;
        float q  = dx * t0 + dy * t1 + dz * t2;      // 0.5*log2e*mahal
        float alpha = __builtin_amdgcn_exp2f(g[9] - q);
        float w = T * alpha;
        T = fmaf(-alpha, T, T);

        const float4* __restrict__ f4 = &fsh[n * (NF / 4)];  // wave-uniform LDS broadcast
#pragma unroll
        for (int j = 0; j < 8; ++j) {
            float4 f = f4[j];
            acc[4 * j + 0] = fmaf(w, f.x, acc[4 * j + 0]);
            acc[4 * j + 1] = fmaf(w, f.y, acc[4 * j + 1]);
            acc[4 * j + 2] = fmaf(w, f.z, acc[4 * j + 2]);
            acc[4 * j + 3] = fmaf(w, f.w, acc[4 * j + 3]);
        }
    }

    float4* __restrict__ o4 = (float4*)(out + p * NF);
#pragma unroll
    for (int j = 0; j < 8; ++j)
        o4[j] = make_float4(acc[4 * j + 0], acc[4 * j + 1],
                            acc[4 * j + 2], acc[4 * j + 3]);
}

extern "C" void kernel_launch(void* const* d_in, const int* in_sizes, int n_in,
                              void* d_out, int out_size, void* d_ws, size_t ws_size,
                              hipStream_t stream)
{
    const float* means  = (const float*)d_in[0];   // (512,3)
    const float* scales = (const float*)d_in[1];   // (512,3)
    const float* rots   = (const float*)d_in[2];   // (512,4)
    const float* opac   = (const float*)d_in[3];   // (512,1)
    const float* feats  = (const float*)d_in[4];   // (512,32)
    const float* cam    = (const float*)d_in[5];   // (4,4)
    const float* coords = (const float*)d_in[6];   // (96,96,16,3)
    float* out = (float*)d_out;                    // (96,96,16,32) fp32

    float* gp = (float*)d_ws;                      // 512*12 floats = 24 KiB

    gr_prep<<<(NG + 255) / 256, 256, 0, stream>>>(means, scales, rots, opac, cam, gp);
    gr_render<<<NP / TPB, TPB, 0, stream>>>(gp, feats, coords, out);
}

// Round 5
// 193.102 us; speedup vs baseline: 2.2167x; 1.2681x over previous
//
#include <hip/hip_runtime.h>

#define NG 512
#define NF 32
#define NP (96 * 96 * 16)   // 147456 points
#define TPB 256             // points per block (= threads)
#define CHUNK 32            // gaussians per produce/consume chunk (MFMA K)
#define NCHUNK (NG / CHUNK) // 16

#define W_STRIDE 17         // dwords per point row in W LDS (16 f16-pairs + 1 pad, odd -> 2-way = free)
#define FT_STRIDE 260       // dwords per feature row in featsT LDS (256 k-pairs + 4 pad, 16B-aligned rows)

typedef _Float16 half8 __attribute__((ext_vector_type(8)));
typedef __fp16  fp16x2 __attribute__((ext_vector_type(2)));   // cvt_pkrtz return type
typedef float f32x4 __attribute__((ext_vector_type(4)));
typedef unsigned uint4v __attribute__((ext_vector_type(4)));

union H2U { fp16x2 h; unsigned u; };
union FRAG { unsigned u[4]; uint4v v; half8 h; };

// gp packed params: 12 floats per gaussian
// [mx,my,mz, A00,A01,A02,A11,A12,A22, lop2, pad, pad]
// A = inv_cov * 0.5*log2(e); lop2 = log2(opacity): alpha = exp2(lop2 - d^T A d)

__global__ __launch_bounds__(256) void gr_prep(
    const float* __restrict__ means,
    const float* __restrict__ scales,
    const float* __restrict__ rots,
    const float* __restrict__ opac,
    const float* __restrict__ cam,
    float* __restrict__ gp)
{
    int n = blockIdx.x * blockDim.x + threadIdx.x;
    if (n >= NG) return;

    float mx = means[n * 3 + 0];
    float my = means[n * 3 + 1];
    float mz = means[n * 3 + 2];

    float h0 = cam[0]  * mx + cam[1]  * my + cam[2]  * mz + cam[3];
    float h1 = cam[4]  * mx + cam[5]  * my + cam[6]  * mz + cam[7];
    float h2 = cam[8]  * mx + cam[9]  * my + cam[10] * mz + cam[11];
    float h3 = cam[12] * mx + cam[13] * my + cam[14] * mz + cam[15];
    float ih3 = 1.0f / h3;
    mx = h0 * ih3; my = h1 * ih3; mz = h2 * ih3;

    float qw = rots[n * 4 + 0];
    float qx = rots[n * 4 + 1];
    float qy = rots[n * 4 + 2];
    float qz = rots[n * 4 + 3];
    float qinv = 1.0f / sqrtf(qw * qw + qx * qx + qy * qy + qz * qz);
    qw *= qinv; qx *= qinv; qy *= qinv; qz *= qinv;

    float R00 = 1.0f - 2.0f * (qy * qy + qz * qz);
    float R01 = 2.0f * (qx * qy - qw * qz);
    float R02 = 2.0f * (qx * qz + qw * qy);
    float R10 = 2.0f * (qx * qy + qw * qz);
    float R11 = 1.0f - 2.0f * (qx * qx + qz * qz);
    float R12 = 2.0f * (qy * qz - qw * qx);
    float R20 = 2.0f * (qx * qz - qw * qy);
    float R21 = 2.0f * (qy * qz + qw * qx);
    float R22 = 1.0f - 2.0f * (qx * qx + qy * qy);

    float s0 = scales[n * 3 + 0];
    float s1 = scales[n * 3 + 1];
    float s2 = scales[n * 3 + 2];
    // cov = R diag(s^2) R^T => inv_cov = R diag(s^-2) R^T; fold 0.5*log2(e)
    const float es = 0.7213475204444817f;
    float i0 = es / (s0 * s0);
    float i1 = es / (s1 * s1);
    float i2 = es / (s2 * s2);

    float a00 = R00 * R00 * i0 + R01 * R01 * i1 + R02 * R02 * i2;
    float a01 = R00 * R10 * i0 + R01 * R11 * i1 + R02 * R12 * i2;
    float a02 = R00 * R20 * i0 + R01 * R21 * i1 + R02 * R22 * i2;
    float a11 = R10 * R10 * i0 + R11 * R11 * i1 + R12 * R12 * i2;
    float a12 = R10 * R20 * i0 + R11 * R21 * i1 + R12 * R22 * i2;
    float a22 = R20 * R20 * i0 + R21 * R21 * i1 + R22 * R22 * i2;

    float* g = gp + n * 12;
    g[0] = mx;  g[1] = my;  g[2] = mz;
    g[3] = a00; g[4] = a01; g[5] = a02;
    g[6] = a11; g[7] = a12; g[8] = a22;
    g[9] = __log2f(opac[n]);
    g[10] = 0.0f; g[11] = 0.0f;
}

// Transpose feats (512,32) fp32 -> featsT f16-pair dwords in ws, laid out
// exactly as the render kernel's LDS image: row n (feature), dword kp holds
// f16 pair (feats[2kp][n], feats[2kp+1][n]); row stride FT_STRIDE dwords.
__global__ __launch_bounds__(256) void gr_featpack(
    const float* __restrict__ feats,
    unsigned* __restrict__ ft)
{
    int t = threadIdx.x;
    for (int i = 0; i < 32; ++i) {
        int pid = t + 256 * i;          // 8192 pairs total
        int n  = pid & 31;
        int kp = pid >> 5;              // 0..255
        float a = feats[(2 * kp) * NF + n];
        float b = feats[(2 * kp + 1) * NF + n];
        H2U p; p.h = __builtin_amdgcn_cvt_pkrtz(a, b);
        ft[n * FT_STRIDE + kp] = p.u;
    }
}

__global__ __launch_bounds__(256) void gr_render(
    const float* __restrict__ gp,
    const unsigned* __restrict__ ft,   // packed featsT image in ws
    const float* __restrict__ coords,
    float* __restrict__ out)
{
    __shared__ unsigned ftlds[NF * FT_STRIDE];   // 8320 dw = 33280 B
    __shared__ unsigned wlds[TPB * W_STRIDE];    // 4352 dw = 17408 B

    const int tid = threadIdx.x;

    // Stage featsT (16B-aligned b128 copies)
    {
        const uint4v* __restrict__ src = (const uint4v*)ft;
        for (int i = tid; i < NF * FT_STRIDE / 4; i += TPB)
            *(uint4v*)&ftlds[i * 4] = src[i];
    }
    __syncthreads();

    const int p = blockIdx.x * TPB + tid;
    const float cx = coords[p * 3 + 0];
    const float cy = coords[p * 3 + 1];
    const float cz = coords[p * 3 + 2];

    const int ln   = tid & 15;        // MFMA lane col
    const int quad = (tid >> 4) & 3;  // MFMA lane quad
    const int wv   = tid >> 6;        // wave id (owns points wv*64..wv*64+63)

    f32x4 acc[4][2];
#pragma unroll
    for (int mt = 0; mt < 4; ++mt)
#pragma unroll
        for (int nt = 0; nt < 2; ++nt)
            acc[mt][nt] = (f32x4){0.f, 0.f, 0.f, 0.f};

    float T = 1.0f;

#pragma unroll 1
    for (int c = 0; c < NCHUNK; ++c) {
        // ---- produce: 32 weights for this thread's point -> W LDS (f16 pairs)
        // gp addressing is loop-uniform -> scalar s_load path (R2 lesson).
#pragma unroll
        for (int j = 0; j < CHUNK / 2; ++j) {
            const float* __restrict__ g0 = gp + (c * CHUNK + 2 * j) * 12;
            const float* __restrict__ g1 = g0 + 12;

            float dx = cx - g0[0], dy = cy - g0[1], dz = cz - g0[2];
            float t0 = g0[3] * dx + g0[4] * dy + g0[5] * dz;
            float t1 = g0[4] * dx + g0[6] * dy + g0[7] * dz;
            float t2 = g0[5] * dx + g0[7] * dy + g0[8] * dz;
            float q  = dx * t0 + dy * t1 + dz * t2;
            float alpha = __builtin_amdgcn_exp2f(g0[9] - q);
            float w0 = T * alpha;
            T = fmaf(-alpha, T, T);

            dx = cx - g1[0]; dy = cy - g1[1]; dz = cz - g1[2];
            t0 = g1[3] * dx + g1[4] * dy + g1[5] * dz;
            t1 = g1[4] * dx + g1[6] * dy + g1[7] * dz;
            t2 = g1[5] * dx + g1[7] * dy + g1[8] * dz;
            q  = dx * t0 + dy * t1 + dz * t2;
            alpha = __builtin_amdgcn_exp2f(g1[9] - q);
            float w1 = T * alpha;
            T = fmaf(-alpha, T, T);

            H2U pk; pk.h = __builtin_amdgcn_cvt_pkrtz(w0, w1);
            wlds[tid * W_STRIDE + j] = pk.u;
        }

        // ---- consume: MFMA over this wave's own 64 points (intra-wave LDS
        // producer->consumer; no barrier needed, lgkmcnt orders it)
        FRAG bf0, bf1;
        bf0.v = *(const uint4v*)&ftlds[(0 * 16 + ln) * FT_STRIDE + c * 16 + quad * 4];
        bf1.v = *(const uint4v*)&ftlds[(1 * 16 + ln) * FT_STRIDE + c * 16 + quad * 4];

#pragma unroll
        for (int mt = 0; mt < 4; ++mt) {
            const int row = wv * 64 + mt * 16 + ln;
            const unsigned* __restrict__ wr = &wlds[row * W_STRIDE + quad * 4];
            FRAG af;
            af.u[0] = wr[0]; af.u[1] = wr[1]; af.u[2] = wr[2]; af.u[3] = wr[3];
            acc[mt][0] = __builtin_amdgcn_mfma_f32_16x16x32_f16(af.h, bf0.h, acc[mt][0], 0, 0, 0);
            acc[mt][1] = __builtin_amdgcn_mfma_f32_16x16x32_f16(af.h, bf1.h, acc[mt][1], 0, 0, 0);
        }
    }

    // ---- epilogue: D[row][col] with row=(quad*4+r), col=ln per tile
    float* __restrict__ ob = out + (blockIdx.x * TPB + wv * 64) * NF;
#pragma unroll
    for (int mt = 0; mt < 4; ++mt)
#pragma unroll
        for (int nt = 0; nt < 2; ++nt)
#pragma unroll
            for (int r = 0; r < 4; ++r)
                ob[(mt * 16 + quad * 4 + r) * NF + nt * 16 + ln] = acc[mt][nt][r];
}

extern "C" void kernel_launch(void* const* d_in, const int* in_sizes, int n_in,
                              void* d_out, int out_size, void* d_ws, size_t ws_size,
                              hipStream_t stream)
{
    const float* means  = (const float*)d_in[0];   // (512,3)
    const float* scales = (const float*)d_in[1];   // (512,3)
    const float* rots   = (const float*)d_in[2];   // (512,4)
    const float* opac   = (const float*)d_in[3];   // (512,1)
    const float* feats  = (const float*)d_in[4];   // (512,32)
    const float* cam    = (const float*)d_in[5];   // (4,4)
    const float* coords = (const float*)d_in[6];   // (96,96,16,3)
    float* out = (float*)d_out;                    // (96,96,16,32) fp32

    float*    gp = (float*)d_ws;                           // 24 KiB
    unsigned* ft = (unsigned*)((char*)d_ws + NG * 12 * 4); // 33.3 KiB featsT image

    gr_prep<<<(NG + 255) / 256, 256, 0, stream>>>(means, scales, rots, opac, cam, gp);
    gr_featpack<<<1, 256, 0, stream>>>(feats, ft);
    gr_render<<<NP / TPB, TPB, 0, stream>>>(gp, ft, coords, out);
}

// Round 6
// 155.322 us; speedup vs baseline: 2.7558x; 1.2432x over previous
//
#include <hip/hip_runtime.h>

#define NG 512
#define NF 32
#define NP (96 * 96 * 16)   // 147456 points
#define TPB 256             // points per block (= threads)
#define CHUNK 32            // gaussians per produce/consume chunk (MFMA K)
#define NCHUNK (NG / CHUNK) // 16

#define W_STRIDE 17         // dwords per point row in W LDS (16 f16-pairs + 1 pad; odd -> conflict-free writes)

typedef _Float16 half8 __attribute__((ext_vector_type(8)));
typedef __fp16  fp16x2 __attribute__((ext_vector_type(2)));   // cvt_pkrtz return type
typedef float f32x4 __attribute__((ext_vector_type(4)));
typedef unsigned uint4v __attribute__((ext_vector_type(4)));

union H2U { fp16x2 h; unsigned u; };
union FRAG { unsigned u[4]; uint4v v; half8 h; };

// gp packed params: 12 floats per gaussian
// [mx,my,mz, a00 | a01,a02,a11,a12 | a22, lop2, pad, pad]
// A-matrix = inv_cov * 0.5*log2(e); lop2 = log2(opacity): alpha = exp2(lop2 - d^T A d)

__global__ __launch_bounds__(256) void gr_prep(
    const float* __restrict__ means,
    const float* __restrict__ scales,
    const float* __restrict__ rots,
    const float* __restrict__ opac,
    const float* __restrict__ cam,
    float* __restrict__ gp)
{
    int n = blockIdx.x * blockDim.x + threadIdx.x;
    if (n >= NG) return;

    float mx = means[n * 3 + 0];
    float my = means[n * 3 + 1];
    float mz = means[n * 3 + 2];

    float h0 = cam[0]  * mx + cam[1]  * my + cam[2]  * mz + cam[3];
    float h1 = cam[4]  * mx + cam[5]  * my + cam[6]  * mz + cam[7];
    float h2 = cam[8]  * mx + cam[9]  * my + cam[10] * mz + cam[11];
    float h3 = cam[12] * mx + cam[13] * my + cam[14] * mz + cam[15];
    float ih3 = 1.0f / h3;
    mx = h0 * ih3; my = h1 * ih3; mz = h2 * ih3;

    float qw = rots[n * 4 + 0];
    float qx = rots[n * 4 + 1];
    float qy = rots[n * 4 + 2];
    float qz = rots[n * 4 + 3];
    float qinv = 1.0f / sqrtf(qw * qw + qx * qx + qy * qy + qz * qz);
    qw *= qinv; qx *= qinv; qy *= qinv; qz *= qinv;

    float R00 = 1.0f - 2.0f * (qy * qy + qz * qz);
    float R01 = 2.0f * (qx * qy - qw * qz);
    float R02 = 2.0f * (qx * qz + qw * qy);
    float R10 = 2.0f * (qx * qy + qw * qz);
    float R11 = 1.0f - 2.0f * (qx * qx + qz * qz);
    float R12 = 2.0f * (qy * qz - qw * qx);
    float R20 = 2.0f * (qx * qz - qw * qy);
    float R21 = 2.0f * (qy * qz + qw * qx);
    float R22 = 1.0f - 2.0f * (qx * qx + qy * qy);

    float s0 = scales[n * 3 + 0];
    float s1 = scales[n * 3 + 1];
    float s2 = scales[n * 3 + 2];
    // cov = R diag(s^2) R^T => inv_cov = R diag(s^-2) R^T; fold 0.5*log2(e)
    const float es = 0.7213475204444817f;
    float i0 = es / (s0 * s0);
    float i1 = es / (s1 * s1);
    float i2 = es / (s2 * s2);

    float a00 = R00 * R00 * i0 + R01 * R01 * i1 + R02 * R02 * i2;
    float a01 = R00 * R10 * i0 + R01 * R11 * i1 + R02 * R12 * i2;
    float a02 = R00 * R20 * i0 + R01 * R21 * i1 + R02 * R22 * i2;
    float a11 = R10 * R10 * i0 + R11 * R11 * i1 + R12 * R12 * i2;
    float a12 = R10 * R20 * i0 + R11 * R21 * i1 + R12 * R22 * i2;
    float a22 = R20 * R20 * i0 + R21 * R21 * i1 + R22 * R22 * i2;

    float* g = gp + n * 12;
    g[0] = mx;  g[1] = my;  g[2] = mz;
    g[3] = a00; g[4] = a01; g[5] = a02;
    g[6] = a11; g[7] = a12; g[8] = a22;
    g[9] = __log2f(opac[n]);
    g[10] = 0.0f; g[11] = 0.0f;
}

// Pack feats (512,32) fp32 into MFMA B-fragment lane order, f16 pairs.
// Layout: dword d = c*512 + nt*256 + lane*4 + jp holds f16 pair for
// B[n = nt*16 + (lane&15)][k = c*32 + (lane>>4)*8 + 2jp + {0,1}]
// (verified fragment mapping from R5: lane l holds k = (l>>4)*8 + j).
// Render then loads each frag with ONE coalesced global_load_dwordx4.
__global__ __launch_bounds__(256) void gr_featpack(
    const float* __restrict__ feats,
    unsigned* __restrict__ ftg)
{
    int d = blockIdx.x * 256 + threadIdx.x;   // 0..8191
    int c  = d >> 9;
    int r  = d & 511;
    int nt = r >> 8;
    int l  = (r >> 2) & 63;
    int jp = r & 3;
    int n  = nt * 16 + (l & 15);
    int k0 = c * 32 + (l >> 4) * 8 + 2 * jp;
    float a = feats[k0 * NF + n];
    float b = feats[(k0 + 1) * NF + n];
    H2U p; p.h = __builtin_amdgcn_cvt_pkrtz(a, b);
    ftg[d] = p.u;
}

__global__ __launch_bounds__(256) void gr_render(
    const float* __restrict__ gp,
    const unsigned* __restrict__ ftg,   // B-frag-ordered feats image in ws
    const float* __restrict__ coords,
    float* __restrict__ out)
{
    __shared__ float4  gsh[NG * 3];              // 24576 B: gaussian params
    __shared__ unsigned wlds[TPB * W_STRIDE];    // 17408 B: weight rows

    const int tid = threadIdx.x;

    // Stage gp into LDS (b128 copies); inner-loop param reads become
    // wave-uniform ds_read_b128 broadcasts (R5 lesson: scalar s_load path
    // serializes at ~1 L2 latency per iteration).
    {
        const float4* __restrict__ src = (const float4*)gp;
#pragma unroll
        for (int i = 0; i < 6; ++i)
            gsh[tid + 256 * i] = src[tid + 256 * i];
    }
    __syncthreads();

    const int p = blockIdx.x * TPB + tid;
    const float cx = coords[p * 3 + 0];
    const float cy = coords[p * 3 + 1];
    const float cz = coords[p * 3 + 2];

    const int ln   = tid & 15;        // MFMA lane col
    const int quad = (tid >> 4) & 3;  // MFMA lane quad
    const int wv   = tid >> 6;        // wave id (owns points wv*64..wv*64+63)
    const int lane = tid & 63;

    f32x4 acc[4][2];
#pragma unroll
    for (int mt = 0; mt < 4; ++mt)
#pragma unroll
        for (int nt = 0; nt < 2; ++nt)
            acc[mt][nt] = (f32x4){0.f, 0.f, 0.f, 0.f};

    float T = 1.0f;

#pragma unroll 1
    for (int c = 0; c < NCHUNK; ++c) {
        // B-frags: one coalesced dwordx4 per frag, issued now, used after
        // produce (self-hiding latency; 16 KB total -> L2-hot).
        FRAG bf0, bf1;
        bf0.v = ((const uint4v*)(ftg + c * 512 +   0))[lane];
        bf1.v = ((const uint4v*)(ftg + c * 512 + 256))[lane];

        // ---- produce: 32 weights for this thread's point -> W LDS (f16 pairs)
#pragma unroll
        for (int j = 0; j < CHUNK / 2; ++j) {
            const float4* __restrict__ g0 = &gsh[(c * CHUNK + 2 * j) * 3];

            float4 A0 = g0[0], B0 = g0[1], C0 = g0[2];
            float dx = cx - A0.x, dy = cy - A0.y, dz = cz - A0.z;
            float t0 = A0.w * dx + B0.x * dy + B0.y * dz;
            float t1 = B0.x * dx + B0.z * dy + B0.w * dz;
            float t2 = B0.y * dx + B0.w * dy + C0.x * dz;
            float q  = dx * t0 + dy * t1 + dz * t2;
            float alpha = __builtin_amdgcn_exp2f(C0.y - q);
            float w0 = T * alpha;
            T = fmaf(-alpha, T, T);

            float4 A1 = g0[3], B1 = g0[4], C1 = g0[5];
            dx = cx - A1.x; dy = cy - A1.y; dz = cz - A1.z;
            t0 = A1.w * dx + B1.x * dy + B1.y * dz;
            t1 = B1.x * dx + B1.z * dy + B1.w * dz;
            t2 = B1.y * dx + B1.w * dy + C1.x * dz;
            q  = dx * t0 + dy * t1 + dz * t2;
            alpha = __builtin_amdgcn_exp2f(C1.y - q);
            float w1 = T * alpha;
            T = fmaf(-alpha, T, T);

            H2U pk; pk.h = __builtin_amdgcn_cvt_pkrtz(w0, w1);
            wlds[tid * W_STRIDE + j] = pk.u;
        }

        // ---- consume: MFMA over this wave's own 64 points (intra-wave LDS
        // producer->consumer; wave-ordered LDS pipe, no barrier needed)
#pragma unroll
        for (int mt = 0; mt < 4; ++mt) {
            const int row = wv * 64 + mt * 16 + ln;
            const unsigned* __restrict__ wr = &wlds[row * W_STRIDE + quad * 4];
            FRAG af;
            af.u[0] = wr[0]; af.u[1] = wr[1]; af.u[2] = wr[2]; af.u[3] = wr[3];
            acc[mt][0] = __builtin_amdgcn_mfma_f32_16x16x32_f16(af.h, bf0.h, acc[mt][0], 0, 0, 0);
            acc[mt][1] = __builtin_amdgcn_mfma_f32_16x16x32_f16(af.h, bf1.h, acc[mt][1], 0, 0, 0);
        }
    }

    // ---- epilogue: D[row][col] with row=(quad*4+r), col=ln per tile (R5-verified)
    float* __restrict__ ob = out + (blockIdx.x * TPB + wv * 64) * NF;
#pragma unroll
    for (int mt = 0; mt < 4; ++mt)
#pragma unroll
        for (int nt = 0; nt < 2; ++nt)
#pragma unroll
            for (int r = 0; r < 4; ++r)
                ob[(mt * 16 + quad * 4 + r) * NF + nt * 16 + ln] = acc[mt][nt][r];
}

extern "C" void kernel_launch(void* const* d_in, const int* in_sizes, int n_in,
                              void* d_out, int out_size, void* d_ws, size_t ws_size,
                              hipStream_t stream)
{
    const float* means  = (const float*)d_in[0];   // (512,3)
    const float* scales = (const float*)d_in[1];   // (512,3)
    const float* rots   = (const float*)d_in[2];   // (512,4)
    const float* opac   = (const float*)d_in[3];   // (512,1)
    const float* feats  = (const float*)d_in[4];   // (512,32)
    const float* cam    = (const float*)d_in[5];   // (4,4)
    const float* coords = (const float*)d_in[6];   // (96,96,16,3)
    float* out = (float*)d_out;                    // (96,96,16,32) fp32

    float*    gp  = (float*)d_ws;                            // 24 KiB
    unsigned* ftg = (unsigned*)((char*)d_ws + NG * 12 * 4);  // 32 KiB frag image

    gr_prep<<<(NG + 255) / 256, 256, 0, stream>>>(means, scales, rots, opac, cam, gp);
    gr_featpack<<<32, 256, 0, stream>>>(feats, ftg);
    gr_render<<<NP / TPB, TPB, 0, stream>>>(gp, ftg, coords, out);
}

// Round 7
// 103.732 us; speedup vs baseline: 4.1264x; 1.4973x over previous
//
#include <hip/hip_runtime.h>

#define NG 512
#define NF 32
#define NP (96 * 96 * 16)   // 147456 points
#define TPB 256             // points per block (= threads)
#define NCHUNK 16           // 512 gaussians / 32 per chunk

typedef _Float16 half8 __attribute__((ext_vector_type(8)));
typedef __fp16  fp16x2 __attribute__((ext_vector_type(2)));
typedef float f32x4 __attribute__((ext_vector_type(4)));
typedef unsigned uint4v __attribute__((ext_vector_type(4)));
typedef unsigned uint2v __attribute__((ext_vector_type(2)));

union H2U { fp16x2 h; unsigned u; };
union FRAG { unsigned u[4]; uint4v v; half8 h; };

__device__ __forceinline__ unsigned packh(__fp16 a, __fp16 b) {
    H2U p; p.h = (fp16x2){a, b}; return p.u;
}
__device__ __forceinline__ unsigned pkrtz(float a, float b) {
    H2U p; p.h = __builtin_amdgcn_cvt_pkrtz(a, b); return p.u;
}
// Swizzled dword index into the [256 rows][16 dw] LDS image: XOR the b128
// group index with (row&3) -> bank-balanced for both per-row and per-column
// access patterns while keeping 16B alignment.
__device__ __forceinline__ int ridx(int row, int grp) {
    return row * 16 + 4 * (grp ^ (row & 3));
}

// ---------------------------------------------------------------------------
// gr_pack: blocks 0-1 build the psi A-frag image (gaussian coefficient rows,
// hi/lo f16 split, MFMA A-operand lane order). Blocks 2-33 build the feats
// B-frag image (identical math to R6's verified featpack).
//
// psi'[k] slots (K=32): 0-9 psi_hi, 10-19 psi_lo, 20-29 psi_hi, 30-31 zero.
// phi'[k] slots:        0-9 phi_hi, 10-19 phi_hi, 20-29 phi_lo, 30-31 zero.
// Q = phi'.psi' = hi.hi + hi.lo + lo.hi  (compensated, ~21-bit accurate).
// psi is NEGATED so alpha = exp2(Q).
// ---------------------------------------------------------------------------
__global__ __launch_bounds__(256) void gr_pack(
    const float* __restrict__ means,
    const float* __restrict__ scales,
    const float* __restrict__ rots,
    const float* __restrict__ opac,
    const float* __restrict__ cam,
    const float* __restrict__ feats,
    unsigned* __restrict__ psi,
    unsigned* __restrict__ ftg)
{
    const int b = blockIdx.x;
    const int tid = threadIdx.x;

    if (b < 2) {
        const int n = b * 256 + tid;   // 0..511

        float mx = means[n * 3 + 0];
        float my = means[n * 3 + 1];
        float mz = means[n * 3 + 2];

        float h0 = cam[0]  * mx + cam[1]  * my + cam[2]  * mz + cam[3];
        float h1 = cam[4]  * mx + cam[5]  * my + cam[6]  * mz + cam[7];
        float h2 = cam[8]  * mx + cam[9]  * my + cam[10] * mz + cam[11];
        float h3 = cam[12] * mx + cam[13] * my + cam[14] * mz + cam[15];
        float ih3 = 1.0f / h3;
        mx = h0 * ih3; my = h1 * ih3; mz = h2 * ih3;

        float qw = rots[n * 4 + 0];
        float qx = rots[n * 4 + 1];
        float qy = rots[n * 4 + 2];
        float qz = rots[n * 4 + 3];
        float qinv = 1.0f / sqrtf(qw * qw + qx * qx + qy * qy + qz * qz);
        qw *= qinv; qx *= qinv; qy *= qinv; qz *= qinv;

        float R00 = 1.0f - 2.0f * (qy * qy + qz * qz);
        float R01 = 2.0f * (qx * qy - qw * qz);
        float R02 = 2.0f * (qx * qz + qw * qy);
        float R10 = 2.0f * (qx * qy + qw * qz);
        float R11 = 1.0f - 2.0f * (qx * qx + qz * qz);
        float R12 = 2.0f * (qy * qz - qw * qx);
        float R20 = 2.0f * (qx * qz - qw * qy);
        float R21 = 2.0f * (qy * qz + qw * qx);
        float R22 = 1.0f - 2.0f * (qx * qx + qy * qy);

        float s0 = scales[n * 3 + 0];
        float s1 = scales[n * 3 + 1];
        float s2 = scales[n * 3 + 2];
        // inv_cov = R diag(s^-2) R^T, scaled by 0.5*log2(e)
        const float es = 0.7213475204444817f;
        float i0 = es / (s0 * s0);
        float i1 = es / (s1 * s1);
        float i2 = es / (s2 * s2);

        float a00 = R00 * R00 * i0 + R01 * R01 * i1 + R02 * R02 * i2;
        float a01 = R00 * R10 * i0 + R01 * R11 * i1 + R02 * R12 * i2;
        float a02 = R00 * R20 * i0 + R01 * R21 * i1 + R02 * R22 * i2;
        float a11 = R10 * R10 * i0 + R11 * R11 * i1 + R12 * R12 * i2;
        float a12 = R10 * R20 * i0 + R11 * R21 * i1 + R12 * R22 * i2;
        float a22 = R20 * R20 * i0 + R21 * R21 * i1 + R22 * R22 * i2;

        float amx = a00 * mx + a01 * my + a02 * mz;
        float amy = a01 * mx + a11 * my + a12 * mz;
        float amz = a02 * mx + a12 * my + a22 * mz;

        float psv[10];
        psv[0] = -a00; psv[1] = -a11; psv[2] = -a22;
        psv[3] = -2.0f * a01; psv[4] = -2.0f * a02; psv[5] = -2.0f * a12;
        psv[6] = 2.0f * amx; psv[7] = 2.0f * amy; psv[8] = 2.0f * amz;
        psv[9] = __log2f(opac[n]) - (mx * amx + my * amy + mz * amz);

        __fp16 s[32];
#pragma unroll
        for (int i = 0; i < 10; ++i) {
            __fp16 hi = (__fp16)psv[i];
            __fp16 lo = (__fp16)(psv[i] - (float)hi);
            s[i] = hi; s[10 + i] = lo; s[20 + i] = hi;
        }
        s[30] = (__fp16)0.f; s[31] = (__fp16)0.f;

        // A-frag image: lane l of tile (n>>4) holds k=(l>>4)*8+j for gaussian
        // row (l&15). Write this gaussian's 16 pair-dwords.
        unsigned* base = psi + (n >> 4) * 256;
        const int lr = n & 15;
#pragma unroll
        for (int q = 0; q < 4; ++q)
#pragma unroll
            for (int jp = 0; jp < 4; ++jp)
                base[(lr + 16 * q) * 4 + jp] = packh(s[8 * q + 2 * jp], s[8 * q + 2 * jp + 1]);
    } else {
        // feats B-frag image (R6-verified layout)
        int d = (b - 2) * 256 + tid;   // 0..8191
        int c  = d >> 9;
        int r  = d & 511;
        int nt = r >> 8;
        int l  = (r >> 2) & 63;
        int jp = r & 3;
        int n  = nt * 16 + (l & 15);
        int k0 = c * 32 + (l >> 4) * 8 + 2 * jp;
        ftg[d] = pkrtz(feats[k0 * NF + n], feats[(k0 + 1) * NF + n]);
    }
}

// ---------------------------------------------------------------------------
// gr_render: no __syncthreads anywhere — every LDS access stays within the
// wave's own 64 rows (row = wv*64 + ...), and the per-wave DS pipe is in-order
// (R5/R6-validated premise).
// ---------------------------------------------------------------------------
__global__ __launch_bounds__(256) void gr_render(
    const unsigned* __restrict__ psi,
    const unsigned* __restrict__ ftg,
    const float* __restrict__ coords,
    float* __restrict__ out)
{
    __shared__ uint4v sh4[TPB * 4];          // 16 KB: [256 rows][16 dw] swizzled
    unsigned* sh = (unsigned*)sh4;

    const int tid  = threadIdx.x;
    const int ln   = tid & 15;
    const int quad = (tid >> 4) & 3;
    const int wv   = tid >> 6;
    const int lane = tid & 63;

    const int p = blockIdx.x * TPB + tid;
    const float cx = coords[p * 3 + 0];
    const float cy = coords[p * 3 + 1];
    const float cz = coords[p * 3 + 2];

    // ---- phi' for this point (hi/lo split), staged to LDS, read back as
    // B-frags for the wave's 4 point-tiles.
    {
        float ph[10] = {cx * cx, cy * cy, cz * cz, cx * cy, cx * cz, cy * cz,
                        cx, cy, cz, 1.0f};
        __fp16 s[32];
#pragma unroll
        for (int i = 0; i < 10; ++i) {
            __fp16 hi = (__fp16)ph[i];
            __fp16 lo = (__fp16)(ph[i] - (float)hi);
            s[i] = hi; s[10 + i] = hi; s[20 + i] = lo;
        }
        s[30] = (__fp16)0.f; s[31] = (__fp16)0.f;
#pragma unroll
        for (int i = 0; i < 4; ++i) {
            uint4v v = (uint4v){packh(s[8 * i + 0], s[8 * i + 1]),
                                packh(s[8 * i + 2], s[8 * i + 3]),
                                packh(s[8 * i + 4], s[8 * i + 5]),
                                packh(s[8 * i + 6], s[8 * i + 7])};
            *(uint4v*)&sh[ridx(tid, i)] = v;
        }
    }

    FRAG phif[4];
#pragma unroll
    for (int nt = 0; nt < 4; ++nt)
        phif[nt].v = *(const uint4v*)&sh[ridx(wv * 64 + nt * 16 + ln, quad)];

    f32x4 pvacc[4][2];
#pragma unroll
    for (int mt = 0; mt < 4; ++mt) {
        pvacc[mt][0] = (f32x4){0.f, 0.f, 0.f, 0.f};
        pvacc[mt][1] = (f32x4){0.f, 0.f, 0.f, 0.f};
    }
    float T = 1.0f;

    // prefetch chunk 0 frags
    FRAG pa0, pa1, bf0, bf1;
    pa0.v = ((const uint4v*)(psi + 0 * 256))[lane];
    pa1.v = ((const uint4v*)(psi + 1 * 256))[lane];
    bf0.v = ((const uint4v*)(ftg + 0))[lane];
    bf1.v = ((const uint4v*)(ftg + 256))[lane];

#pragma unroll 1
    for (int c = 0; c < NCHUNK; ++c) {
        // prefetch next chunk (wraps on last iter; harmless)
        const int cn = (c + 1) & (NCHUNK - 1);
        FRAG npa0, npa1, nbf0, nbf1;
        npa0.v = ((const uint4v*)(psi + (2 * cn + 0) * 256))[lane];
        npa1.v = ((const uint4v*)(psi + (2 * cn + 1) * 256))[lane];
        nbf0.v = ((const uint4v*)(ftg + cn * 512 + 0))[lane];
        nbf1.v = ((const uint4v*)(ftg + cn * 512 + 256))[lane];

        // ---- Q GEMM: D[gaussian][point] for 32 gaussians x wave's 64 points
        f32x4 qa[2][4];
#pragma unroll
        for (int nt = 0; nt < 4; ++nt) {
            qa[0][nt] = __builtin_amdgcn_mfma_f32_16x16x32_f16(
                pa0.h, phif[nt].h, (f32x4){0.f, 0.f, 0.f, 0.f}, 0, 0, 0);
            qa[1][nt] = __builtin_amdgcn_mfma_f32_16x16x32_f16(
                pa1.h, phif[nt].h, (f32x4){0.f, 0.f, 0.f, 0.f}, 0, 0, 0);
        }

        // ---- alpha = exp2(Q); transpose to point-rows via LDS (f16 pairs)
#pragma unroll
        for (int m = 0; m < 2; ++m)
#pragma unroll
            for (int nt = 0; nt < 4; ++nt) {
                float a0 = __builtin_amdgcn_exp2f(qa[m][nt][0]);
                float a1 = __builtin_amdgcn_exp2f(qa[m][nt][1]);
                float a2 = __builtin_amdgcn_exp2f(qa[m][nt][2]);
                float a3 = __builtin_amdgcn_exp2f(qa[m][nt][3]);
                const int row = wv * 64 + nt * 16 + ln;
                const int dbase = row * 16 + ((m * 8 + quad * 2) ^ (4 * (row & 3)));
                *(uint2v*)&sh[dbase] = (uint2v){pkrtz(a0, a1), pkrtz(a2, a3)};
            }

        // ---- T-chain on own point's 32 alphas (in gaussian order)
        uint4v a4[4];
#pragma unroll
        for (int i = 0; i < 4; ++i)
            a4[i] = *(const uint4v*)&sh[ridx(tid, i)];

        unsigned wd[16];
#pragma unroll
        for (int g = 0; g < 16; ++g) {
            H2U pp; pp.u = a4[g >> 2][g & 3];
            float al0 = (float)pp.h[0];
            float al1 = (float)pp.h[1];
            float w0 = T * al0; T = fmaf(-al0, T, T);
            float w1 = T * al1; T = fmaf(-al1, T, T);
            wd[g] = pkrtz(w0, w1);
        }
#pragma unroll
        for (int i = 0; i < 4; ++i)
            *(uint4v*)&sh[ridx(tid, i)] =
                (uint4v){wd[4 * i + 0], wd[4 * i + 1], wd[4 * i + 2], wd[4 * i + 3]};

        // ---- PV GEMM: out[point][feature] += W x feats (R6-verified path)
#pragma unroll
        for (int mt = 0; mt < 4; ++mt) {
            FRAG af;
            af.v = *(const uint4v*)&sh[ridx(wv * 64 + mt * 16 + ln, quad)];
            pvacc[mt][0] = __builtin_amdgcn_mfma_f32_16x16x32_f16(af.h, bf0.h, pvacc[mt][0], 0, 0, 0);
            pvacc[mt][1] = __builtin_amdgcn_mfma_f32_16x16x32_f16(af.h, bf1.h, pvacc[mt][1], 0, 0, 0);
        }

        pa0 = npa0; pa1 = npa1; bf0 = nbf0; bf1 = nbf1;
    }

    // ---- epilogue: D[row][col], row=(quad*4+r), col=ln (R5/R6-verified)
    float* __restrict__ ob = out + (blockIdx.x * TPB + wv * 64) * NF;
#pragma unroll
    for (int mt = 0; mt < 4; ++mt)
#pragma unroll
        for (int nt = 0; nt < 2; ++nt)
#pragma unroll
            for (int r = 0; r < 4; ++r)
                ob[(mt * 16 + quad * 4 + r) * NF + nt * 16 + ln] = pvacc[mt][nt][r];
}

extern "C" void kernel_launch(void* const* d_in, const int* in_sizes, int n_in,
                              void* d_out, int out_size, void* d_ws, size_t ws_size,
                              hipStream_t stream)
{
    const float* means  = (const float*)d_in[0];   // (512,3)
    const float* scales = (const float*)d_in[1];   // (512,3)
    const float* rots   = (const float*)d_in[2];   // (512,4)
    const float* opac   = (const float*)d_in[3];   // (512,1)
    const float* feats  = (const float*)d_in[4];   // (512,32)
    const float* cam    = (const float*)d_in[5];   // (4,4)
    const float* coords = (const float*)d_in[6];   // (96,96,16,3)
    float* out = (float*)d_out;                    // (96,96,16,32) fp32

    unsigned* psi = (unsigned*)d_ws;               // 32 KiB: gaussian A-frag image
    unsigned* ftg = psi + 32 * 256;                // 32 KiB: feats B-frag image

    gr_pack<<<34, 256, 0, stream>>>(means, scales, rots, opac, cam, feats, psi, ftg);
    gr_render<<<NP / TPB, TPB, 0, stream>>>(psi, ftg, coords, out);
}

// Round 8
// 97.114 us; speedup vs baseline: 4.4076x; 1.0682x over previous
//
#include <hip/hip_runtime.h>

#define NG 512
#define NF 32
#define NP (96 * 96 * 16)   // 147456 points
#define TPB 256             // 4 waves; 64 points per block, 4 gaussian segments
#define PTS 64
#define NSEG 4
#define CPS 4               // chunks (of 32 gaussians) per segment

typedef _Float16 half8 __attribute__((ext_vector_type(8)));
typedef __fp16  fp16x2 __attribute__((ext_vector_type(2)));
typedef float f32x4 __attribute__((ext_vector_type(4)));
typedef unsigned uint4v __attribute__((ext_vector_type(4)));
typedef unsigned uint2v __attribute__((ext_vector_type(2)));

union H2U { fp16x2 h; unsigned u; };
union FRAG { unsigned u[4]; uint4v v; half8 h; };

__device__ __forceinline__ unsigned packh(__fp16 a, __fp16 b) {
    H2U p; p.h = (fp16x2){a, b}; return p.u;
}
__device__ __forceinline__ unsigned pkrtz(float a, float b) {
    H2U p; p.h = __builtin_amdgcn_cvt_pkrtz(a, b); return p.u;
}
// Swizzled dword index into a [256 rows][16 dw] LDS image (bank-balanced,
// 16B-aligned) — R7-verified.
__device__ __forceinline__ int ridx(int row, int grp) {
    return row * 16 + 4 * (grp ^ (row & 3));
}

// ---------------------------------------------------------------------------
// gr_pack (R7-verified): blocks 0-1 psi A-frag image (hi/lo f16 split, MFMA
// A-operand order); blocks 2-33 feats B-frag image.
// ---------------------------------------------------------------------------
__global__ __launch_bounds__(256) void gr_pack(
    const float* __restrict__ means,
    const float* __restrict__ scales,
    const float* __restrict__ rots,
    const float* __restrict__ opac,
    const float* __restrict__ cam,
    const float* __restrict__ feats,
    unsigned* __restrict__ psi,
    unsigned* __restrict__ ftg)
{
    const int b = blockIdx.x;
    const int tid = threadIdx.x;

    if (b < 2) {
        const int n = b * 256 + tid;   // 0..511

        float mx = means[n * 3 + 0];
        float my = means[n * 3 + 1];
        float mz = means[n * 3 + 2];

        float h0 = cam[0]  * mx + cam[1]  * my + cam[2]  * mz + cam[3];
        float h1 = cam[4]  * mx + cam[5]  * my + cam[6]  * mz + cam[7];
        float h2 = cam[8]  * mx + cam[9]  * my + cam[10] * mz + cam[11];
        float h3 = cam[12] * mx + cam[13] * my + cam[14] * mz + cam[15];
        float ih3 = 1.0f / h3;
        mx = h0 * ih3; my = h1 * ih3; mz = h2 * ih3;

        float qw = rots[n * 4 + 0];
        float qx = rots[n * 4 + 1];
        float qy = rots[n * 4 + 2];
        float qz = rots[n * 4 + 3];
        float qinv = 1.0f / sqrtf(qw * qw + qx * qx + qy * qy + qz * qz);
        qw *= qinv; qx *= qinv; qy *= qinv; qz *= qinv;

        float R00 = 1.0f - 2.0f * (qy * qy + qz * qz);
        float R01 = 2.0f * (qx * qy - qw * qz);
        float R02 = 2.0f * (qx * qz + qw * qy);
        float R10 = 2.0f * (qx * qy + qw * qz);
        float R11 = 1.0f - 2.0f * (qx * qx + qz * qz);
        float R12 = 2.0f * (qy * qz - qw * qx);
        float R20 = 2.0f * (qx * qz - qw * qy);
        float R21 = 2.0f * (qy * qz + qw * qx);
        float R22 = 1.0f - 2.0f * (qx * qx + qy * qy);

        float s0 = scales[n * 3 + 0];
        float s1 = scales[n * 3 + 1];
        float s2 = scales[n * 3 + 2];
        const float es = 0.7213475204444817f;   // 0.5*log2(e)
        float i0 = es / (s0 * s0);
        float i1 = es / (s1 * s1);
        float i2 = es / (s2 * s2);

        float a00 = R00 * R00 * i0 + R01 * R01 * i1 + R02 * R02 * i2;
        float a01 = R00 * R10 * i0 + R01 * R11 * i1 + R02 * R12 * i2;
        float a02 = R00 * R20 * i0 + R01 * R21 * i1 + R02 * R22 * i2;
        float a11 = R10 * R10 * i0 + R11 * R11 * i1 + R12 * R12 * i2;
        float a12 = R10 * R20 * i0 + R11 * R21 * i1 + R12 * R22 * i2;
        float a22 = R20 * R20 * i0 + R21 * R21 * i1 + R22 * R22 * i2;

        float amx = a00 * mx + a01 * my + a02 * mz;
        float amy = a01 * mx + a11 * my + a12 * mz;
        float amz = a02 * mx + a12 * my + a22 * mz;

        float psv[10];
        psv[0] = -a00; psv[1] = -a11; psv[2] = -a22;
        psv[3] = -2.0f * a01; psv[4] = -2.0f * a02; psv[5] = -2.0f * a12;
        psv[6] = 2.0f * amx; psv[7] = 2.0f * amy; psv[8] = 2.0f * amz;
        psv[9] = __log2f(opac[n]) - (mx * amx + my * amy + mz * amz);

        __fp16 s[32];
#pragma unroll
        for (int i = 0; i < 10; ++i) {
            __fp16 hi = (__fp16)psv[i];
            __fp16 lo = (__fp16)(psv[i] - (float)hi);
            s[i] = hi; s[10 + i] = lo; s[20 + i] = hi;
        }
        s[30] = (__fp16)0.f; s[31] = (__fp16)0.f;

        unsigned* base = psi + (n >> 4) * 256;
        const int lr = n & 15;
#pragma unroll
        for (int q = 0; q < 4; ++q)
#pragma unroll
            for (int jp = 0; jp < 4; ++jp)
                base[(lr + 16 * q) * 4 + jp] = packh(s[8 * q + 2 * jp], s[8 * q + 2 * jp + 1]);
    } else {
        int d = (b - 2) * 256 + tid;   // 0..8191
        int c  = d >> 9;
        int r  = d & 511;
        int nt = r >> 8;
        int l  = (r >> 2) & 63;
        int jp = r & 3;
        int n  = nt * 16 + (l & 15);
        int k0 = c * 32 + (l >> 4) * 8 + 2 * jp;
        ftg[d] = pkrtz(feats[k0 * NF + n], feats[(k0 + 1) * NF + n]);
    }
}

// ---------------------------------------------------------------------------
// gr_render: 64 points/block, 4 waves = 4 gaussian segments of 128. All LDS
// traffic in the main loop is wave-private (rows wv*64..wv*64+63); the single
// __syncthreads is before the segment-composition epilogue.
// ---------------------------------------------------------------------------
__global__ __launch_bounds__(256) void gr_render(
    const unsigned* __restrict__ psi,
    const unsigned* __restrict__ ftg,
    const float* __restrict__ coords,
    float* __restrict__ out)
{
    __shared__ uint4v sh4[TPB * 4];          // 16 KB: [256 rows][16 dw]
    __shared__ float tT[NSEG][PTS];          // 1 KB: segment transmittances
    unsigned* sh = (unsigned*)sh4;

    const int tid  = threadIdx.x;
    const int ln   = tid & 15;
    const int quad = (tid >> 4) & 3;
    const int wv   = tid >> 6;
    const int lane = tid & 63;

    const int p = blockIdx.x * PTS + lane;   // this lane's point (same 64 pts all waves)
    const float cx = coords[p * 3 + 0];
    const float cy = coords[p * 3 + 1];
    const float cz = coords[p * 3 + 2];

    // ---- phi' (hi/lo split) -> own wave's LDS rows -> B-frags (R7-verified)
    {
        float ph[10] = {cx * cx, cy * cy, cz * cz, cx * cy, cx * cz, cy * cz,
                        cx, cy, cz, 1.0f};
        __fp16 s[32];
#pragma unroll
        for (int i = 0; i < 10; ++i) {
            __fp16 hi = (__fp16)ph[i];
            __fp16 lo = (__fp16)(ph[i] - (float)hi);
            s[i] = hi; s[10 + i] = hi; s[20 + i] = lo;
        }
        s[30] = (__fp16)0.f; s[31] = (__fp16)0.f;
#pragma unroll
        for (int i = 0; i < 4; ++i) {
            uint4v v = (uint4v){packh(s[8 * i + 0], s[8 * i + 1]),
                                packh(s[8 * i + 2], s[8 * i + 3]),
                                packh(s[8 * i + 4], s[8 * i + 5]),
                                packh(s[8 * i + 6], s[8 * i + 7])};
            *(uint4v*)&sh[ridx(tid, i)] = v;
        }
    }

    FRAG phif[4];
#pragma unroll
    for (int nt = 0; nt < 4; ++nt)
        phif[nt].v = *(const uint4v*)&sh[ridx(wv * 64 + nt * 16 + ln, quad)];

    f32x4 pvacc[4][2];
#pragma unroll
    for (int mt = 0; mt < 4; ++mt) {
        pvacc[mt][0] = (f32x4){0.f, 0.f, 0.f, 0.f};
        pvacc[mt][1] = (f32x4){0.f, 0.f, 0.f, 0.f};
    }
    float T = 1.0f;

    // prefetch this wave's first chunk (global chunk id = wv*CPS + cc)
    FRAG pa0, pa1, bf0, bf1;
    {
        const int c0 = wv * CPS;
        pa0.v = ((const uint4v*)(psi + (2 * c0 + 0) * 256))[lane];
        pa1.v = ((const uint4v*)(psi + (2 * c0 + 1) * 256))[lane];
        bf0.v = ((const uint4v*)(ftg + c0 * 512 + 0))[lane];
        bf1.v = ((const uint4v*)(ftg + c0 * 512 + 256))[lane];
    }

#pragma unroll 1
    for (int cc = 0; cc < CPS; ++cc) {
        const int cn = wv * CPS + ((cc + 1) & (CPS - 1));   // wraps; harmless
        FRAG npa0, npa1, nbf0, nbf1;
        npa0.v = ((const uint4v*)(psi + (2 * cn + 0) * 256))[lane];
        npa1.v = ((const uint4v*)(psi + (2 * cn + 1) * 256))[lane];
        nbf0.v = ((const uint4v*)(ftg + cn * 512 + 0))[lane];
        nbf1.v = ((const uint4v*)(ftg + cn * 512 + 256))[lane];

        // ---- Q GEMM: 32 gaussians x this wave's 64 points
        f32x4 qa[2][4];
#pragma unroll
        for (int nt = 0; nt < 4; ++nt) {
            qa[0][nt] = __builtin_amdgcn_mfma_f32_16x16x32_f16(
                pa0.h, phif[nt].h, (f32x4){0.f, 0.f, 0.f, 0.f}, 0, 0, 0);
            qa[1][nt] = __builtin_amdgcn_mfma_f32_16x16x32_f16(
                pa1.h, phif[nt].h, (f32x4){0.f, 0.f, 0.f, 0.f}, 0, 0, 0);
        }

        // ---- alpha = exp2(Q) -> point-row transpose via own LDS rows
#pragma unroll
        for (int m = 0; m < 2; ++m)
#pragma unroll
            for (int nt = 0; nt < 4; ++nt) {
                float a0 = __builtin_amdgcn_exp2f(qa[m][nt][0]);
                float a1 = __builtin_amdgcn_exp2f(qa[m][nt][1]);
                float a2 = __builtin_amdgcn_exp2f(qa[m][nt][2]);
                float a3 = __builtin_amdgcn_exp2f(qa[m][nt][3]);
                const int row = wv * 64 + nt * 16 + ln;
                const int dbase = row * 16 + ((m * 8 + quad * 2) ^ (4 * (row & 3)));
                *(uint2v*)&sh[dbase] = (uint2v){pkrtz(a0, a1), pkrtz(a2, a3)};
            }

        // ---- T-chain on own point's 32 alphas (gaussian order within segment)
        uint4v a4[4];
#pragma unroll
        for (int i = 0; i < 4; ++i)
            a4[i] = *(const uint4v*)&sh[ridx(tid, i)];

        unsigned wd[16];
#pragma unroll
        for (int g = 0; g < 16; ++g) {
            H2U pp; pp.u = a4[g >> 2][g & 3];
            float al0 = (float)pp.h[0];
            float al1 = (float)pp.h[1];
            float w0 = T * al0; T = fmaf(-al0, T, T);
            float w1 = T * al1; T = fmaf(-al1, T, T);
            wd[g] = pkrtz(w0, w1);
        }
#pragma unroll
        for (int i = 0; i < 4; ++i)
            *(uint4v*)&sh[ridx(tid, i)] =
                (uint4v){wd[4 * i + 0], wd[4 * i + 1], wd[4 * i + 2], wd[4 * i + 3]};

        // ---- PV GEMM (R6/R7-verified path)
#pragma unroll
        for (int mt = 0; mt < 4; ++mt) {
            FRAG af;
            af.v = *(const uint4v*)&sh[ridx(wv * 64 + mt * 16 + ln, quad)];
            pvacc[mt][0] = __builtin_amdgcn_mfma_f32_16x16x32_f16(af.h, bf0.h, pvacc[mt][0], 0, 0, 0);
            pvacc[mt][1] = __builtin_amdgcn_mfma_f32_16x16x32_f16(af.h, bf1.h, pvacc[mt][1], 0, 0, 0);
        }

        pa0 = npa0; pa1 = npa1; bf0 = nbf0; bf1 = nbf1;
    }

    // ---- write segment partials (f16 feature-pairs) into own rows (alphas
    // are dead); dword d of row p holds features (d, d+16). |acc| <= max|feat|
    // since sum(w) <= 1, so f16 ulp ~0.004 here.
    tT[wv][lane] = T;
#pragma unroll
    for (int mt = 0; mt < 4; ++mt)
#pragma unroll
        for (int r = 0; r < 4; ++r)
            sh[(wv * 64 + mt * 16 + quad * 4 + r) * 16 + ln] =
                pkrtz(pvacc[mt][0][r], pvacc[mt][1][r]);

    __syncthreads();

    // ---- compose segments: out = sum_s (prod_{s'<s} T_s') * acc_s
    {
        const int pp = tid >> 2;        // point 0..63
        const int g  = tid & 3;         // dword group (4 dwords)
        float t0 = tT[0][pp], t1 = tT[1][pp], t2 = tT[2][pp];
        float w1 = t0, w2 = t0 * t1, w3 = w2 * t2;

        float o[8];
        uint4v v0 = *(const uint4v*)&sh[(0 * 64 + pp) * 16 + g * 4];
#pragma unroll
        for (int j = 0; j < 4; ++j) {
            H2U u; u.u = v0[j];
            o[j] = (float)u.h[0]; o[4 + j] = (float)u.h[1];
        }
        uint4v v1 = *(const uint4v*)&sh[(1 * 64 + pp) * 16 + g * 4];
#pragma unroll
        for (int j = 0; j < 4; ++j) {
            H2U u; u.u = v1[j];
            o[j] = fmaf(w1, (float)u.h[0], o[j]);
            o[4 + j] = fmaf(w1, (float)u.h[1], o[4 + j]);
        }
        uint4v v2 = *(const uint4v*)&sh[(2 * 64 + pp) * 16 + g * 4];
#pragma unroll
        for (int j = 0; j < 4; ++j) {
            H2U u; u.u = v2[j];
            o[j] = fmaf(w2, (float)u.h[0], o[j]);
            o[4 + j] = fmaf(w2, (float)u.h[1], o[4 + j]);
        }
        uint4v v3 = *(const uint4v*)&sh[(3 * 64 + pp) * 16 + g * 4];
#pragma unroll
        for (int j = 0; j < 4; ++j) {
            H2U u; u.u = v3[j];
            o[j] = fmaf(w3, (float)u.h[0], o[j]);
            o[4 + j] = fmaf(w3, (float)u.h[1], o[4 + j]);
        }

        float* __restrict__ ob = out + (blockIdx.x * PTS + pp) * NF + g * 4;
        *(float4*)ob        = make_float4(o[0], o[1], o[2], o[3]);
        *(float4*)(ob + 16) = make_float4(o[4], o[5], o[6], o[7]);
    }
}

extern "C" void kernel_launch(void* const* d_in, const int* in_sizes, int n_in,
                              void* d_out, int out_size, void* d_ws, size_t ws_size,
                              hipStream_t stream)
{
    const float* means  = (const float*)d_in[0];   // (512,3)
    const float* scales = (const float*)d_in[1];   // (512,3)
    const float* rots   = (const float*)d_in[2];   // (512,4)
    const float* opac   = (const float*)d_in[3];   // (512,1)
    const float* feats  = (const float*)d_in[4];   // (512,32)
    const float* cam    = (const float*)d_in[5];   // (4,4)
    const float* coords = (const float*)d_in[6];   // (96,96,16,3)
    float* out = (float*)d_out;                    // (96,96,16,32) fp32

    unsigned* psi = (unsigned*)d_ws;               // 32 KiB: gaussian A-frag image
    unsigned* ftg = psi + 32 * 256;                // 32 KiB: feats B-frag image

    gr_pack<<<34, 256, 0, stream>>>(means, scales, rots, opac, cam, feats, psi, ftg);
    gr_render<<<NP / PTS, TPB, 0, stream>>>(psi, ftg, coords, out);
}

// Round 9
// 95.985 us; speedup vs baseline: 4.4595x; 1.0118x over previous
//
#include <hip/hip_runtime.h>

#define NG 512
#define NF 32
#define NP (96 * 96 * 16)   // 147456 points
#define TPB 256             // 4 waves; 64 points per block, 4 gaussian segments
#define PTS 64
#define NSEG 4
#define CPS 4               // chunks (of 32 gaussians) per segment

typedef _Float16 half8 __attribute__((ext_vector_type(8)));
typedef __fp16  fp16x2 __attribute__((ext_vector_type(2)));
typedef float f32x4 __attribute__((ext_vector_type(4)));
typedef unsigned uint4v __attribute__((ext_vector_type(4)));
typedef unsigned uint2v __attribute__((ext_vector_type(2)));

union H2U { fp16x2 h; unsigned u; };
union FRAG { unsigned u[4]; uint4v v; half8 h; };

__device__ __forceinline__ unsigned packh(__fp16 a, __fp16 b) {
    H2U p; p.h = (fp16x2){a, b}; return p.u;
}
__device__ __forceinline__ unsigned pkrtz(float a, float b) {
    H2U p; p.h = __builtin_amdgcn_cvt_pkrtz(a, b); return p.u;
}
// Swizzled dword index into a [256 rows][16 dw] LDS image (bank-balanced,
// 16B-aligned) — R7/R8-verified.
__device__ __forceinline__ int ridx(int row, int grp) {
    return row * 16 + 4 * (grp ^ (row & 3));
}

// ---------------------------------------------------------------------------
// gr_pack (R7/R8-verified): blocks 0-1 psi A-frag image (hi/lo f16 split,
// MFMA A-operand order); blocks 2-33 feats B-frag image.
// ---------------------------------------------------------------------------
__global__ __launch_bounds__(256) void gr_pack(
    const float* __restrict__ means,
    const float* __restrict__ scales,
    const float* __restrict__ rots,
    const float* __restrict__ opac,
    const float* __restrict__ cam,
    const float* __restrict__ feats,
    unsigned* __restrict__ psi,
    unsigned* __restrict__ ftg)
{
    const int b = blockIdx.x;
    const int tid = threadIdx.x;

    if (b < 2) {
        const int n = b * 256 + tid;   // 0..511

        float mx = means[n * 3 + 0];
        float my = means[n * 3 + 1];
        float mz = means[n * 3 + 2];

        float h0 = cam[0]  * mx + cam[1]  * my + cam[2]  * mz + cam[3];
        float h1 = cam[4]  * mx + cam[5]  * my + cam[6]  * mz + cam[7];
        float h2 = cam[8]  * mx + cam[9]  * my + cam[10] * mz + cam[11];
        float h3 = cam[12] * mx + cam[13] * my + cam[14] * mz + cam[15];
        float ih3 = 1.0f / h3;
        mx = h0 * ih3; my = h1 * ih3; mz = h2 * ih3;

        float qw = rots[n * 4 + 0];
        float qx = rots[n * 4 + 1];
        float qy = rots[n * 4 + 2];
        float qz = rots[n * 4 + 3];
        float qinv = 1.0f / sqrtf(qw * qw + qx * qx + qy * qy + qz * qz);
        qw *= qinv; qx *= qinv; qy *= qinv; qz *= qinv;

        float R00 = 1.0f - 2.0f * (qy * qy + qz * qz);
        float R01 = 2.0f * (qx * qy - qw * qz);
        float R02 = 2.0f * (qx * qz + qw * qy);
        float R10 = 2.0f * (qx * qy + qw * qz);
        float R11 = 1.0f - 2.0f * (qx * qx + qz * qz);
        float R12 = 2.0f * (qy * qz - qw * qx);
        float R20 = 2.0f * (qx * qz - qw * qy);
        float R21 = 2.0f * (qy * qz + qw * qx);
        float R22 = 1.0f - 2.0f * (qx * qx + qy * qy);

        float s0 = scales[n * 3 + 0];
        float s1 = scales[n * 3 + 1];
        float s2 = scales[n * 3 + 2];
        const float es = 0.7213475204444817f;   // 0.5*log2(e)
        float i0 = es / (s0 * s0);
        float i1 = es / (s1 * s1);
        float i2 = es / (s2 * s2);

        float a00 = R00 * R00 * i0 + R01 * R01 * i1 + R02 * R02 * i2;
        float a01 = R00 * R10 * i0 + R01 * R11 * i1 + R02 * R12 * i2;
        float a02 = R00 * R20 * i0 + R01 * R21 * i1 + R02 * R22 * i2;
        float a11 = R10 * R10 * i0 + R11 * R11 * i1 + R12 * R12 * i2;
        float a12 = R10 * R20 * i0 + R11 * R21 * i1 + R12 * R22 * i2;
        float a22 = R20 * R20 * i0 + R21 * R21 * i1 + R22 * R22 * i2;

        float amx = a00 * mx + a01 * my + a02 * mz;
        float amy = a01 * mx + a11 * my + a12 * mz;
        float amz = a02 * mx + a12 * my + a22 * mz;

        float psv[10];
        psv[0] = -a00; psv[1] = -a11; psv[2] = -a22;
        psv[3] = -2.0f * a01; psv[4] = -2.0f * a02; psv[5] = -2.0f * a12;
        psv[6] = 2.0f * amx; psv[7] = 2.0f * amy; psv[8] = 2.0f * amz;
        psv[9] = __log2f(opac[n]) - (mx * amx + my * amy + mz * amz);

        __fp16 s[32];
#pragma unroll
        for (int i = 0; i < 10; ++i) {
            __fp16 hi = (__fp16)psv[i];
            __fp16 lo = (__fp16)(psv[i] - (float)hi);
            s[i] = hi; s[10 + i] = lo; s[20 + i] = hi;
        }
        s[30] = (__fp16)0.f; s[31] = (__fp16)0.f;

        unsigned* base = psi + (n >> 4) * 256;
        const int lr = n & 15;
#pragma unroll
        for (int q = 0; q < 4; ++q)
#pragma unroll
            for (int jp = 0; jp < 4; ++jp)
                base[(lr + 16 * q) * 4 + jp] = packh(s[8 * q + 2 * jp], s[8 * q + 2 * jp + 1]);
    } else {
        int d = (b - 2) * 256 + tid;   // 0..8191
        int c  = d >> 9;
        int r  = d & 511;
        int nt = r >> 8;
        int l  = (r >> 2) & 63;
        int jp = r & 3;
        int n  = nt * 16 + (l & 15);
        int k0 = c * 32 + (l >> 4) * 8 + 2 * jp;
        ftg[d] = pkrtz(feats[k0 * NF + n], feats[(k0 + 1) * NF + n]);
    }
}

// ---------------------------------------------------------------------------
// gr_render: 64 points/block, 4 waves = 4 gaussian segments of 128.
// R9: register-pressure diet — no explicit double-buffer (L2 covers refetch),
// m-loop split (halves live qa), bf frags loaded mid-chunk, launch_bounds
// min-waves=5 to pin VGPR<=102 -> 5 blocks/CU (vs ~3 in R8).
// ---------------------------------------------------------------------------
__global__ __launch_bounds__(256, 5) void gr_render(
    const unsigned* __restrict__ psi,
    const unsigned* __restrict__ ftg,
    const float* __restrict__ coords,
    float* __restrict__ out)
{
    __shared__ uint4v sh4[TPB * 4];          // 16 KB: [256 rows][16 dw]
    __shared__ float tT[NSEG][PTS];          // 1 KB: segment transmittances
    unsigned* sh = (unsigned*)sh4;

    const int tid  = threadIdx.x;
    const int ln   = tid & 15;
    const int quad = (tid >> 4) & 3;
    const int wv   = tid >> 6;
    const int lane = tid & 63;

    const int p = blockIdx.x * PTS + lane;   // this lane's point
    const float cx = coords[p * 3 + 0];
    const float cy = coords[p * 3 + 1];
    const float cz = coords[p * 3 + 2];

    // ---- phi' (hi/lo split) -> own wave's LDS rows -> B-frags (R7-verified)
    {
        float ph[10] = {cx * cx, cy * cy, cz * cz, cx * cy, cx * cz, cy * cz,
                        cx, cy, cz, 1.0f};
        __fp16 s[32];
#pragma unroll
        for (int i = 0; i < 10; ++i) {
            __fp16 hi = (__fp16)ph[i];
            __fp16 lo = (__fp16)(ph[i] - (float)hi);
            s[i] = hi; s[10 + i] = hi; s[20 + i] = lo;
        }
        s[30] = (__fp16)0.f; s[31] = (__fp16)0.f;
#pragma unroll
        for (int i = 0; i < 4; ++i) {
            uint4v v = (uint4v){packh(s[8 * i + 0], s[8 * i + 1]),
                                packh(s[8 * i + 2], s[8 * i + 3]),
                                packh(s[8 * i + 4], s[8 * i + 5]),
                                packh(s[8 * i + 6], s[8 * i + 7])};
            *(uint4v*)&sh[ridx(tid, i)] = v;
        }
    }

    FRAG phif[4];
#pragma unroll
    for (int nt = 0; nt < 4; ++nt)
        phif[nt].v = *(const uint4v*)&sh[ridx(wv * 64 + nt * 16 + ln, quad)];

    f32x4 pvacc[4][2];
#pragma unroll
    for (int mt = 0; mt < 4; ++mt) {
        pvacc[mt][0] = (f32x4){0.f, 0.f, 0.f, 0.f};
        pvacc[mt][1] = (f32x4){0.f, 0.f, 0.f, 0.f};
    }
    float T = 1.0f;

#pragma unroll 1
    for (int cc = 0; cc < CPS; ++cc) {
        const int c = wv * CPS + cc;   // this wave's global chunk id

        // ---- Q GEMM + exp2, m-tile at a time (halves live MFMA results)
#pragma unroll
        for (int m = 0; m < 2; ++m) {
            FRAG pa;
            pa.v = ((const uint4v*)(psi + (2 * c + m) * 256))[lane];
            f32x4 qa[4];
#pragma unroll
            for (int nt = 0; nt < 4; ++nt)
                qa[nt] = __builtin_amdgcn_mfma_f32_16x16x32_f16(
                    pa.h, phif[nt].h, (f32x4){0.f, 0.f, 0.f, 0.f}, 0, 0, 0);
#pragma unroll
            for (int nt = 0; nt < 4; ++nt) {
                float a0 = __builtin_amdgcn_exp2f(qa[nt][0]);
                float a1 = __builtin_amdgcn_exp2f(qa[nt][1]);
                float a2 = __builtin_amdgcn_exp2f(qa[nt][2]);
                float a3 = __builtin_amdgcn_exp2f(qa[nt][3]);
                const int row = wv * 64 + nt * 16 + ln;
                const int dbase = row * 16 + ((m * 8 + quad * 2) ^ (4 * (row & 3)));
                *(uint2v*)&sh[dbase] = (uint2v){pkrtz(a0, a1), pkrtz(a2, a3)};
            }
        }

        // ---- issue bf loads now; consumed after T-chain (~400 cyc of cover)
        FRAG bf0, bf1;
        bf0.v = ((const uint4v*)(ftg + c * 512 + 0))[lane];
        bf1.v = ((const uint4v*)(ftg + c * 512 + 256))[lane];

        // ---- T-chain on own point's 32 alphas (gaussian order in segment)
#pragma unroll
        for (int i = 0; i < 4; ++i) {
            uint4v a4 = *(const uint4v*)&sh[ridx(tid, i)];
            uint4v w4;
#pragma unroll
            for (int g = 0; g < 4; ++g) {
                H2U pp; pp.u = a4[g];
                float al0 = (float)pp.h[0];
                float al1 = (float)pp.h[1];
                float w0 = T * al0; T = fmaf(-al0, T, T);
                float w1 = T * al1; T = fmaf(-al1, T, T);
                w4[g] = pkrtz(w0, w1);
            }
            *(uint4v*)&sh[ridx(tid, i)] = w4;
        }

        // ---- PV GEMM (R6/R7/R8-verified path)
#pragma unroll
        for (int mt = 0; mt < 4; ++mt) {
            FRAG af;
            af.v = *(const uint4v*)&sh[ridx(wv * 64 + mt * 16 + ln, quad)];
            pvacc[mt][0] = __builtin_amdgcn_mfma_f32_16x16x32_f16(af.h, bf0.h, pvacc[mt][0], 0, 0, 0);
            pvacc[mt][1] = __builtin_amdgcn_mfma_f32_16x16x32_f16(af.h, bf1.h, pvacc[mt][1], 0, 0, 0);
        }
    }

    // ---- write segment partials (f16 feature-pairs) into own rows; dword d
    // of row p holds features (d, d+16). |acc| <= max|feat| since sum(w)<=1.
    tT[wv][lane] = T;
#pragma unroll
    for (int mt = 0; mt < 4; ++mt)
#pragma unroll
        for (int r = 0; r < 4; ++r)
            sh[(wv * 64 + mt * 16 + quad * 4 + r) * 16 + ln] =
                pkrtz(pvacc[mt][0][r], pvacc[mt][1][r]);

    __syncthreads();

    // ---- compose segments: out = sum_s (prod_{s'<s} T_s') * acc_s
    {
        const int pp = tid >> 2;        // point 0..63
        const int g  = tid & 3;         // dword group (4 dwords)
        float t0 = tT[0][pp], t1 = tT[1][pp], t2 = tT[2][pp];
        float w1 = t0, w2 = t0 * t1, w3 = w2 * t2;

        float o[8];
        uint4v v0 = *(const uint4v*)&sh[(0 * 64 + pp) * 16 + g * 4];
#pragma unroll
        for (int j = 0; j < 4; ++j) {
            H2U u; u.u = v0[j];
            o[j] = (float)u.h[0]; o[4 + j] = (float)u.h[1];
        }
        uint4v v1 = *(const uint4v*)&sh[(1 * 64 + pp) * 16 + g * 4];
#pragma unroll
        for (int j = 0; j < 4; ++j) {
            H2U u; u.u = v1[j];
            o[j] = fmaf(w1, (float)u.h[0], o[j]);
            o[4 + j] = fmaf(w1, (float)u.h[1], o[4 + j]);
        }
        uint4v v2 = *(const uint4v*)&sh[(2 * 64 + pp) * 16 + g * 4];
#pragma unroll
        for (int j = 0; j < 4; ++j) {
            H2U u; u.u = v2[j];
            o[j] = fmaf(w2, (float)u.h[0], o[j]);
            o[4 + j] = fmaf(w2, (float)u.h[1], o[4 + j]);
        }
        uint4v v3 = *(const uint4v*)&sh[(3 * 64 + pp) * 16 + g * 4];
#pragma unroll
        for (int j = 0; j < 4; ++j) {
            H2U u; u.u = v3[j];
            o[j] = fmaf(w3, (float)u.h[0], o[j]);
            o[4 + j] = fmaf(w3, (float)u.h[1], o[4 + j]);
        }

        float* __restrict__ ob = out + (blockIdx.x * PTS + pp) * NF + g * 4;
        *(float4*)ob        = make_float4(o[0], o[1], o[2], o[3]);
        *(float4*)(ob + 16) = make_float4(o[4], o[5], o[6], o[7]);
    }
}

extern "C" void kernel_launch(void* const* d_in, const int* in_sizes, int n_in,
                              void* d_out, int out_size, void* d_ws, size_t ws_size,
                              hipStream_t stream)
{
    const float* means  = (const float*)d_in[0];   // (512,3)
    const float* scales = (const float*)d_in[1];   // (512,3)
    const float* rots   = (const float*)d_in[2];   // (512,4)
    const float* opac   = (const float*)d_in[3];   // (512,1)
    const float* feats  = (const float*)d_in[4];   // (512,32)
    const float* cam    = (const float*)d_in[5];   // (4,4)
    const float* coords = (const float*)d_in[6];   // (96,96,16,3)
    float* out = (float*)d_out;                    // (96,96,16,32) fp32

    unsigned* psi = (unsigned*)d_ws;               // 32 KiB: gaussian A-frag image
    unsigned* ftg = psi + 32 * 256;                // 32 KiB: feats B-frag image

    gr_pack<<<34, 256, 0, stream>>>(means, scales, rots, opac, cam, feats, psi, ftg);
    gr_render<<<NP / PTS, TPB, 0, stream>>>(psi, ftg, coords, out);
}

// Round 10
// 94.869 us; speedup vs baseline: 4.5119x; 1.0118x over previous
//
#include <hip/hip_runtime.h>

#define NG 512
#define NF 32
#define NP (96 * 96 * 16)   // 147456 points
#define TPB 256             // 4 waves; 64 points per block, 4 gaussian segments
#define PTS 64
#define NSEG 4
#define CPS 4               // chunks (of 32 gaussians) per segment

typedef _Float16 half8 __attribute__((ext_vector_type(8)));
typedef __fp16  fp16x2 __attribute__((ext_vector_type(2)));
typedef float f32x4 __attribute__((ext_vector_type(4)));
typedef unsigned uint4v __attribute__((ext_vector_type(4)));
typedef unsigned uint2v __attribute__((ext_vector_type(2)));

union H2U { fp16x2 h; unsigned u; };
union FRAG { unsigned u[4]; uint4v v; half8 h; };

__device__ __forceinline__ unsigned packh(__fp16 a, __fp16 b) {
    H2U p; p.h = (fp16x2){a, b}; return p.u;
}
__device__ __forceinline__ unsigned pkrtz(float a, float b) {
    H2U p; p.h = __builtin_amdgcn_cvt_pkrtz(a, b); return p.u;
}
// Swizzled dword index into a [256 rows][16 dw] LDS image (bank-balanced,
// 16B-aligned) — R7/R8/R9-verified.
__device__ __forceinline__ int ridx(int row, int grp) {
    return row * 16 + 4 * (grp ^ (row & 3));
}

// ---------------------------------------------------------------------------
// gr_pack (R7+-verified): blocks 0-1 psi A-frag image (hi/lo f16 split,
// MFMA A-operand order); blocks 2-33 feats B-frag image.
// ---------------------------------------------------------------------------
__global__ __launch_bounds__(256) void gr_pack(
    const float* __restrict__ means,
    const float* __restrict__ scales,
    const float* __restrict__ rots,
    const float* __restrict__ opac,
    const float* __restrict__ cam,
    const float* __restrict__ feats,
    unsigned* __restrict__ psi,
    unsigned* __restrict__ ftg)
{
    const int b = blockIdx.x;
    const int tid = threadIdx.x;

    if (b < 2) {
        const int n = b * 256 + tid;   // 0..511

        float mx = means[n * 3 + 0];
        float my = means[n * 3 + 1];
        float mz = means[n * 3 + 2];

        float h0 = cam[0]  * mx + cam[1]  * my + cam[2]  * mz + cam[3];
        float h1 = cam[4]  * mx + cam[5]  * my + cam[6]  * mz + cam[7];
        float h2 = cam[8]  * mx + cam[9]  * my + cam[10] * mz + cam[11];
        float h3 = cam[12] * mx + cam[13] * my + cam[14] * mz + cam[15];
        float ih3 = 1.0f / h3;
        mx = h0 * ih3; my = h1 * ih3; mz = h2 * ih3;

        float qw = rots[n * 4 + 0];
        float qx = rots[n * 4 + 1];
        float qy = rots[n * 4 + 2];
        float qz = rots[n * 4 + 3];
        float qinv = 1.0f / sqrtf(qw * qw + qx * qx + qy * qy + qz * qz);
        qw *= qinv; qx *= qinv; qy *= qinv; qz *= qinv;

        float R00 = 1.0f - 2.0f * (qy * qy + qz * qz);
        float R01 = 2.0f * (qx * qy - qw * qz);
        float R02 = 2.0f * (qx * qz + qw * qy);
        float R10 = 2.0f * (qx * qy + qw * qz);
        float R11 = 1.0f - 2.0f * (qx * qx + qz * qz);
        float R12 = 2.0f * (qy * qz - qw * qx);
        float R20 = 2.0f * (qx * qz - qw * qy);
        float R21 = 2.0f * (qy * qz + qw * qx);
        float R22 = 1.0f - 2.0f * (qx * qx + qy * qy);

        float s0 = scales[n * 3 + 0];
        float s1 = scales[n * 3 + 1];
        float s2 = scales[n * 3 + 2];
        const float es = 0.7213475204444817f;   // 0.5*log2(e)
        float i0 = es / (s0 * s0);
        float i1 = es / (s1 * s1);
        float i2 = es / (s2 * s2);

        float a00 = R00 * R00 * i0 + R01 * R01 * i1 + R02 * R02 * i2;
        float a01 = R00 * R10 * i0 + R01 * R11 * i1 + R02 * R12 * i2;
        float a02 = R00 * R20 * i0 + R01 * R21 * i1 + R02 * R22 * i2;
        float a11 = R10 * R10 * i0 + R11 * R11 * i1 + R12 * R12 * i2;
        float a12 = R10 * R20 * i0 + R11 * R21 * i1 + R12 * R22 * i2;
        float a22 = R20 * R20 * i0 + R21 * R21 * i1 + R22 * R22 * i2;

        float amx = a00 * mx + a01 * my + a02 * mz;
        float amy = a01 * mx + a11 * my + a12 * mz;
        float amz = a02 * mx + a12 * my + a22 * mz;

        float psv[10];
        psv[0] = -a00; psv[1] = -a11; psv[2] = -a22;
        psv[3] = -2.0f * a01; psv[4] = -2.0f * a02; psv[5] = -2.0f * a12;
        psv[6] = 2.0f * amx; psv[7] = 2.0f * amy; psv[8] = 2.0f * amz;
        psv[9] = __log2f(opac[n]) - (mx * amx + my * amy + mz * amz);

        __fp16 s[32];
#pragma unroll
        for (int i = 0; i < 10; ++i) {
            __fp16 hi = (__fp16)psv[i];
            __fp16 lo = (__fp16)(psv[i] - (float)hi);
            s[i] = hi; s[10 + i] = lo; s[20 + i] = hi;
        }
        s[30] = (__fp16)0.f; s[31] = (__fp16)0.f;

        unsigned* base = psi + (n >> 4) * 256;
        const int lr = n & 15;
#pragma unroll
        for (int q = 0; q < 4; ++q)
#pragma unroll
            for (int jp = 0; jp < 4; ++jp)
                base[(lr + 16 * q) * 4 + jp] = packh(s[8 * q + 2 * jp], s[8 * q + 2 * jp + 1]);
    } else {
        int d = (b - 2) * 256 + tid;   // 0..8191
        int c  = d >> 9;
        int r  = d & 511;
        int nt = r >> 8;
        int l  = (r >> 2) & 63;
        int jp = r & 3;
        int n  = nt * 16 + (l & 15);
        int k0 = c * 32 + (l >> 4) * 8 + 2 * jp;
        ftg[d] = pkrtz(feats[k0 * NF + n], feats[(k0 + 1) * NF + n]);
    }
}

// ---------------------------------------------------------------------------
// gr_render: 64 points/block, 4 waves = 4 gaussian segments of 128.
// R10: (1) quad-factored T-chain — cumulative (1-a) products computed off the
// T critical path, one serial mul per 4 gaussians (path 256->~32 cyc/chunk);
// (2) all 4 VMEM frag loads hoisted to chunk top (one vmcnt window covers
// them; pa1/bf consumed hundreds of cycles after issue).
// ---------------------------------------------------------------------------
__global__ __launch_bounds__(256, 5) void gr_render(
    const unsigned* __restrict__ psi,
    const unsigned* __restrict__ ftg,
    const float* __restrict__ coords,
    float* __restrict__ out)
{
    __shared__ uint4v sh4[TPB * 4];          // 16 KB: [256 rows][16 dw]
    __shared__ float tT[NSEG][PTS];          // 1 KB: segment transmittances
    unsigned* sh = (unsigned*)sh4;

    const int tid  = threadIdx.x;
    const int ln   = tid & 15;
    const int quad = (tid >> 4) & 3;
    const int wv   = tid >> 6;
    const int lane = tid & 63;

    const int p = blockIdx.x * PTS + lane;   // this lane's point
    const float cx = coords[p * 3 + 0];
    const float cy = coords[p * 3 + 1];
    const float cz = coords[p * 3 + 2];

    // ---- phi' (hi/lo split) -> own wave's LDS rows -> B-frags (R7-verified)
    {
        float ph[10] = {cx * cx, cy * cy, cz * cz, cx * cy, cx * cz, cy * cz,
                        cx, cy, cz, 1.0f};
        __fp16 s[32];
#pragma unroll
        for (int i = 0; i < 10; ++i) {
            __fp16 hi = (__fp16)ph[i];
            __fp16 lo = (__fp16)(ph[i] - (float)hi);
            s[i] = hi; s[10 + i] = hi; s[20 + i] = lo;
        }
        s[30] = (__fp16)0.f; s[31] = (__fp16)0.f;
#pragma unroll
        for (int i = 0; i < 4; ++i) {
            uint4v v = (uint4v){packh(s[8 * i + 0], s[8 * i + 1]),
                                packh(s[8 * i + 2], s[8 * i + 3]),
                                packh(s[8 * i + 4], s[8 * i + 5]),
                                packh(s[8 * i + 6], s[8 * i + 7])};
            *(uint4v*)&sh[ridx(tid, i)] = v;
        }
    }

    FRAG phif[4];
#pragma unroll
    for (int nt = 0; nt < 4; ++nt)
        phif[nt].v = *(const uint4v*)&sh[ridx(wv * 64 + nt * 16 + ln, quad)];

    f32x4 pvacc[4][2];
#pragma unroll
    for (int mt = 0; mt < 4; ++mt) {
        pvacc[mt][0] = (f32x4){0.f, 0.f, 0.f, 0.f};
        pvacc[mt][1] = (f32x4){0.f, 0.f, 0.f, 0.f};
    }
    float T = 1.0f;

#pragma unroll 1
    for (int cc = 0; cc < CPS; ++cc) {
        const int c = wv * CPS + cc;   // this wave's global chunk id

        // ---- hoist all 4 VMEM frag loads; issued back-to-back, one vmcnt
        // window. pa0 consumed ~now, pa1 after m0-phase, bf after T-chain.
        FRAG pa0, pa1, bf0, bf1;
        pa0.v = ((const uint4v*)(psi + (2 * c + 0) * 256))[lane];
        pa1.v = ((const uint4v*)(psi + (2 * c + 1) * 256))[lane];
        bf0.v = ((const uint4v*)(ftg + c * 512 + 0))[lane];
        bf1.v = ((const uint4v*)(ftg + c * 512 + 256))[lane];

        // ---- Q GEMM + exp2, m-tile at a time (caps live MFMA results)
#pragma unroll
        for (int m = 0; m < 2; ++m) {
            const FRAG& pa = m ? pa1 : pa0;
            f32x4 qa[4];
#pragma unroll
            for (int nt = 0; nt < 4; ++nt)
                qa[nt] = __builtin_amdgcn_mfma_f32_16x16x32_f16(
                    pa.h, phif[nt].h, (f32x4){0.f, 0.f, 0.f, 0.f}, 0, 0, 0);
#pragma unroll
            for (int nt = 0; nt < 4; ++nt) {
                float a0 = __builtin_amdgcn_exp2f(qa[nt][0]);
                float a1 = __builtin_amdgcn_exp2f(qa[nt][1]);
                float a2 = __builtin_amdgcn_exp2f(qa[nt][2]);
                float a3 = __builtin_amdgcn_exp2f(qa[nt][3]);
                const int row = wv * 64 + nt * 16 + ln;
                const int dbase = row * 16 + ((m * 8 + quad * 2) ^ (4 * (row & 3)));
                *(uint2v*)&sh[dbase] = (uint2v){pkrtz(a0, a1), pkrtz(a2, a3)};
            }
        }

        // ---- T-chain, quad-factored: per 4 gaussians the cumulative
        // (1-a) products (c1,c2,c3,p) and t_i = c_i*a_i are computed OFF the
        // T dependency; w_i = T*t_i fan out in parallel; only T *= p is
        // serial -> critical path 1 mul per 4 gaussians (was 8 dependent fma).
#pragma unroll
        for (int i = 0; i < 4; ++i) {
            uint4v a4 = *(const uint4v*)&sh[ridx(tid, i)];
            uint4v w4;
#pragma unroll
            for (int h = 0; h < 2; ++h) {
                H2U u0; u0.u = a4[2 * h + 0];
                H2U u1; u1.u = a4[2 * h + 1];
                float a0 = (float)u0.h[0];
                float a1 = (float)u0.h[1];
                float a2 = (float)u1.h[0];
                float a3 = (float)u1.h[1];
                float c1 = 1.0f - a0;
                float t1 = c1 * a1; float c2 = c1 - t1;
                float t2 = c2 * a2; float c3 = c2 - t2;
                float t3 = c3 * a3; float pq = c3 - t3;
                float w0 = T * a0;
                float w1 = T * t1;
                float w2 = T * t2;
                float w3 = T * t3;
                T = T * pq;
                w4[2 * h + 0] = pkrtz(w0, w1);
                w4[2 * h + 1] = pkrtz(w2, w3);
            }
            *(uint4v*)&sh[ridx(tid, i)] = w4;
        }

        // ---- PV GEMM (R6+-verified path)
#pragma unroll
        for (int mt = 0; mt < 4; ++mt) {
            FRAG af;
            af.v = *(const uint4v*)&sh[ridx(wv * 64 + mt * 16 + ln, quad)];
            pvacc[mt][0] = __builtin_amdgcn_mfma_f32_16x16x32_f16(af.h, bf0.h, pvacc[mt][0], 0, 0, 0);
            pvacc[mt][1] = __builtin_amdgcn_mfma_f32_16x16x32_f16(af.h, bf1.h, pvacc[mt][1], 0, 0, 0);
        }
    }

    // ---- write segment partials (f16 feature-pairs) into own rows; dword d
    // of row p holds features (d, d+16). |acc| <= max|feat| since sum(w)<=1.
    tT[wv][lane] = T;
#pragma unroll
    for (int mt = 0; mt < 4; ++mt)
#pragma unroll
        for (int r = 0; r < 4; ++r)
            sh[(wv * 64 + mt * 16 + quad * 4 + r) * 16 + ln] =
                pkrtz(pvacc[mt][0][r], pvacc[mt][1][r]);

    __syncthreads();

    // ---- compose segments: out = sum_s (prod_{s'<s} T_s') * acc_s
    {
        const int pp = tid >> 2;        // point 0..63
        const int g  = tid & 3;         // dword group (4 dwords)
        float t0 = tT[0][pp], t1 = tT[1][pp], t2 = tT[2][pp];
        float w1 = t0, w2 = t0 * t1, w3 = w2 * t2;

        float o[8];
        uint4v v0 = *(const uint4v*)&sh[(0 * 64 + pp) * 16 + g * 4];
#pragma unroll
        for (int j = 0; j < 4; ++j) {
            H2U u; u.u = v0[j];
            o[j] = (float)u.h[0]; o[4 + j] = (float)u.h[1];
        }
        uint4v v1 = *(const uint4v*)&sh[(1 * 64 + pp) * 16 + g * 4];
#pragma unroll
        for (int j = 0; j < 4; ++j) {
            H2U u; u.u = v1[j];
            o[j] = fmaf(w1, (float)u.h[0], o[j]);
            o[4 + j] = fmaf(w1, (float)u.h[1], o[4 + j]);
        }
        uint4v v2 = *(const uint4v*)&sh[(2 * 64 + pp) * 16 + g * 4];
#pragma unroll
        for (int j = 0; j < 4; ++j) {
            H2U u; u.u = v2[j];
            o[j] = fmaf(w2, (float)u.h[0], o[j]);
            o[4 + j] = fmaf(w2, (float)u.h[1], o[4 + j]);
        }
        uint4v v3 = *(const uint4v*)&sh[(3 * 64 + pp) * 16 + g * 4];
#pragma unroll
        for (int j = 0; j < 4; ++j) {
            H2U u; u.u = v3[j];
            o[j] = fmaf(w3, (float)u.h[0], o[j]);
            o[4 + j] = fmaf(w3, (float)u.h[1], o[4 + j]);
        }

        float* __restrict__ ob = out + (blockIdx.x * PTS + pp) * NF + g * 4;
        *(float4*)ob        = make_float4(o[0], o[1], o[2], o[3]);
        *(float4*)(ob + 16) = make_float4(o[4], o[5], o[6], o[7]);
    }
}

extern "C" void kernel_launch(void* const* d_in, const int* in_sizes, int n_in,
                              void* d_out, int out_size, void* d_ws, size_t ws_size,
                              hipStream_t stream)
{
    const float* means  = (const float*)d_in[0];   // (512,3)
    const float* scales = (const float*)d_in[1];   // (512,3)
    const float* rots   = (const float*)d_in[2];   // (512,4)
    const float* opac   = (const float*)d_in[3];   // (512,1)
    const float* feats  = (const float*)d_in[4];   // (512,32)
    const float* cam    = (const float*)d_in[5];   // (4,4)
    const float* coords = (const float*)d_in[6];   // (96,96,16,3)
    float* out = (float*)d_out;                    // (96,96,16,32) fp32

    unsigned* psi = (unsigned*)d_ws;               // 32 KiB: gaussian A-frag image
    unsigned* ftg = psi + 32 * 256;                // 32 KiB: feats B-frag image

    gr_pack<<<34, 256, 0, stream>>>(means, scales, rots, opac, cam, feats, psi, ftg);
    gr_render<<<NP / PTS, TPB, 0, stream>>>(psi, ftg, coords, out);
}